// Round 6
// baseline (408.499 us; speedup 1.0000x reference)
//
#include <hip/hip_runtime.h>
#include <hip/hip_bf16.h>

#define A_TOK 2048
#define DDIM 1024
#define FDIM 2048
#define NEXP 8
#define NE9 9                      // 8 routed + 1 shared pseudo-expert
#define SLOTS_R (2 * A_TOK)        // 4096 routed slots
#define SLOTS_T (SLOTS_R + A_TOK)  // 6144 incl. shared rows
#define NB1 (2 * FDIM)             // 4096: interleaved [w_in | w_swiglu] rows (32-col blocks)

// k_prep job ranges (flat 1-D grid)
#define PREP_TRA_END 8192           // 16 z * 512 tiles
#define PREP_TRB_END (PREP_TRA_END + 4096)   // 8 z * 512 tiles
#define PREP_SH12_END (PREP_TRB_END + 1024)  // 4096 row-jobs / 4
#define PREP_SHOUT_END (PREP_SH12_END + 512) // 1024 rows / 2
#define PREP_NWG (PREP_SHOUT_END + 1)        // +1 zero block

typedef __attribute__((ext_vector_type(8))) short short8v;   // 8 bf16
typedef __attribute__((ext_vector_type(4))) float f32x4;
typedef __attribute__((ext_vector_type(4))) ushort ushort4v;

#define BARRIER() asm volatile("s_barrier" ::: "memory")
#define VMCNT(n) asm volatile("s_waitcnt vmcnt(" #n ")" ::: "memory")

__device__ __forceinline__ void lds16(const void* g, void* l) {
  __builtin_amdgcn_global_load_lds((const __attribute__((address_space(1))) void*)g,
                                   (__attribute__((address_space(3))) void*)l, 16, 0, 0);
}

__device__ __forceinline__ float sigmoidf_(float x) { return 1.f / (1.f + __expf(-x)); }
__device__ __forceinline__ ushort f2bf(float x) {
  __hip_bfloat16 b = __float2bfloat16(x);
  ushort u; __builtin_memcpy(&u, &b, 2); return u;
}
__device__ __forceinline__ float bf2f(ushort u) {
  union { unsigned int i; float f; } x; x.i = (unsigned int)u << 16; return x.f;
}

// ============== consolidated weight prep (one launch) ==============
__global__ void k_prep(const float* __restrict__ w_in_e, const float* __restrict__ w_sw_e,
                       const float* __restrict__ w_out_e, const float* __restrict__ w_in_sh,
                       const float* __restrict__ w_sw_sh, const float* __restrict__ w_out_sh,
                       ushort* __restrict__ wt12, ushort* __restrict__ wt_out_t,
                       int* __restrict__ counts, int* __restrict__ ticket) {
  __shared__ ushort tile[64][68];
  int b = blockIdx.x, tid = threadIdx.x;
  if (b < PREP_TRA_END) {
    // trA: w_in_e/w_sw_e [e][D][F] fp32 -> wt12[e][4096][1024] bf16 (interleaved remap)
    int z = b >> 9, t2 = b & 511;
    int e = z & 7, which = z >> 3;
    const float* in = (which ? w_sw_e : w_in_e) + (size_t)e * DDIM * FDIM;
    ushort* outb = wt12 + (size_t)e * NB1 * DDIM;
    int c0 = (t2 & 31) * 64, r0 = (t2 >> 5) * 64;   // c over F, r over D
    int rr = tid >> 4, cq = tid & 15;
#pragma unroll
    for (int i = 0; i < 4; i++) {
      int r = i * 16 + rr;
      float4 v = *(const float4*)(in + (size_t)(r0 + r) * FDIM + c0 + cq * 4);
      ushort4v o = {f2bf(v.x), f2bf(v.y), f2bf(v.z), f2bf(v.w)};
      *(ushort4v*)&tile[r][cq * 4] = o;
    }
    __syncthreads();
    int cc = tid >> 4, rq = tid & 15;
#pragma unroll
    for (int i = 0; i < 4; i++) {
      int c = i * 16 + cc;
      int f = c0 + c;
      int rp = ((f >> 5) << 6) + (which << 5) + (f & 31);
      ushort4v o = {tile[rq * 4 + 0][c], tile[rq * 4 + 1][c],
                    tile[rq * 4 + 2][c], tile[rq * 4 + 3][c]};
      *(ushort4v*)(outb + (size_t)rp * DDIM + r0 + rq * 4) = o;
    }
  } else if (b < PREP_TRB_END) {
    // trB: w_out_e [e][F][D] fp32 -> wt_out_t [e][D][F] bf16 (plain transpose)
    int b2 = b - PREP_TRA_END;
    int z = b2 >> 9, t2 = b2 & 511;
    const float* in = w_out_e + (size_t)z * FDIM * DDIM;
    ushort* out = wt_out_t + (size_t)z * DDIM * FDIM;
    int c0 = (t2 & 15) * 64, r0 = (t2 >> 4) * 64;   // c over D, r over F
    int rr = tid >> 4, cq = tid & 15;
#pragma unroll
    for (int i = 0; i < 4; i++) {
      int r = i * 16 + rr;
      float4 v = *(const float4*)(in + (size_t)(r0 + r) * DDIM + c0 + cq * 4);
      ushort4v o = {f2bf(v.x), f2bf(v.y), f2bf(v.z), f2bf(v.w)};
      *(ushort4v*)&tile[r][cq * 4] = o;
    }
    __syncthreads();
    int cc = tid >> 4, rq = tid & 15;
#pragma unroll
    for (int i = 0; i < 4; i++) {
      int c = i * 16 + cc;
      ushort4v o = {tile[rq * 4 + 0][c], tile[rq * 4 + 1][c],
                    tile[rq * 4 + 2][c], tile[rq * 4 + 3][c]};
      *(ushort4v*)(out + (size_t)(c0 + c) * FDIM + r0 + rq * 4) = o;
    }
  } else if (b < PREP_SH12_END) {
    // shared in/sw [F][D] -> wt12[8] rows (remap; already K-contiguous)
    int j = b - PREP_TRB_END;
    int rj = j * 4 + (tid >> 6);   // 0..4095
    int l = tid & 63;
    int which = rj & 1, f = rj >> 1;
    const float* src = (which ? w_sw_sh : w_in_sh) + (size_t)f * DDIM;
    int rp = ((f >> 5) << 6) + (which << 5) + (f & 31);
    ushort* dst = wt12 + (size_t)NEXP * NB1 * DDIM + (size_t)rp * DDIM;
#pragma unroll
    for (int i = 0; i < 4; i++) {
      int q = l + 64 * i;
      float4 v = ((const float4*)src)[q];
      ushort4v o = {f2bf(v.x), f2bf(v.y), f2bf(v.z), f2bf(v.w)};
      ((ushort4v*)dst)[q] = o;
    }
  } else if (b < PREP_SHOUT_END) {
    // shared out [D][F] -> wt_out_t[8] rows (plain convert)
    int j = b - PREP_SH12_END;
    int d = j * 2 + (tid >> 7);    // 0..1023
    int l = tid & 127;
    const float* src = w_out_sh + (size_t)d * FDIM;
    ushort* dst = wt_out_t + (size_t)NEXP * DDIM * FDIM + (size_t)d * FDIM;
#pragma unroll
    for (int i = 0; i < 4; i++) {
      int q = l + 128 * i;
      float4 v = ((const float4*)src)[q];
      ushort4v o = {f2bf(v.x), f2bf(v.y), f2bf(v.z), f2bf(v.w)};
      ((ushort4v*)dst)[q] = o;
    }
  } else {
    if (tid < 16) counts[tid] = 0;
    if (tid == 16) *ticket = 0;
  }
}

// ---------------- router (+ fused last-block scan) ----------------
__global__ void k_router(const float* __restrict__ x, const float* __restrict__ rw,
                         __hip_bfloat16* __restrict__ xbf, int* __restrict__ counts,
                         int* __restrict__ top_e, float* __restrict__ top_g,
                         int* __restrict__ offs, int* __restrict__ cursor,
                         int* __restrict__ ticket) {
  int t = blockIdx.x * 4 + (threadIdx.x >> 6);
  int l = threadIdx.x & 63;
  const float* xr = x + (size_t)t * DDIM;
  float acc[NEXP];
#pragma unroll
  for (int e = 0; e < NEXP; e++) acc[e] = 0.f;
#pragma unroll
  for (int i = 0; i < 16; i++) {
    int d = i * 64 + l;
    float v = xr[d];
    xbf[(size_t)t * DDIM + d] = __float2bfloat16(v);
    const float* rr = rw + (size_t)d * NEXP;
#pragma unroll
    for (int e = 0; e < NEXP; e++) acc[e] += v * rr[e];
  }
#pragma unroll
  for (int e = 0; e < NEXP; e++) {
#pragma unroll
    for (int s = 32; s > 0; s >>= 1) acc[e] += __shfl_xor(acc[e], s);
  }
  if (l == 0) {
    float b1 = -1e30f, b2 = -1e30f;
    int i1 = 0, i2 = 0;
#pragma unroll
    for (int e = 0; e < NEXP; e++) {
      float v = acc[e];
      if (v > b1) { b2 = b1; i2 = i1; b1 = v; i1 = e; }
      else if (v > b2) { b2 = v; i2 = e; }
    }
    atomicAdd(&counts[i1], 1);
    atomicAdd(&counts[i2], 1);
    top_e[t * 2 + 0] = i1; top_e[t * 2 + 1] = i2;
    top_g[t * 2 + 0] = sigmoidf_(b1); top_g[t * 2 + 1] = sigmoidf_(b2);
  }
  // fused exclusive scan: last block to finish computes offs/cursor
  __syncthreads();
  if (threadIdx.x == 0) {
    __threadfence();
    int tk = atomicAdd(ticket, 1);
    if (tk == gridDim.x - 1) {
      counts[NEXP] = A_TOK;  // shared pseudo-expert
      int s = 0;
      for (int e = 0; e < NE9; e++) { offs[e] = s; s += counts[e]; cursor[e] = 0; }
      __threadfence();
    }
  }
}

__global__ void k_dispatch(const float* __restrict__ x, const int* __restrict__ top_e,
                           const float* __restrict__ top_g, const int* __restrict__ offs,
                           int* __restrict__ cursor, int* __restrict__ slot_of,
                           __hip_bfloat16* __restrict__ y) {
  int t = blockIdx.x * 4 + (threadIdx.x >> 6);
  int l = threadIdx.x & 63;
  int e0 = top_e[t * 2 + 0], e1 = top_e[t * 2 + 1];
  float g0 = top_g[t * 2 + 0], g1 = top_g[t * 2 + 1];
  int s0 = 0, s1 = 0;
  if (l == 0) {
    s0 = offs[e0] + atomicAdd(&cursor[e0], 1);
    s1 = offs[e1] + atomicAdd(&cursor[e1], 1);
    slot_of[t * 2 + 0] = s0; slot_of[t * 2 + 1] = s1;
  }
  s0 = __shfl(s0, 0); s1 = __shfl(s1, 0);
  const float* xr = x + (size_t)t * DDIM;
#pragma unroll
  for (int i = 0; i < 16; i++) {
    int d = i * 64 + l;
    float v = xr[d];
    y[(size_t)s0 * DDIM + d] = __float2bfloat16(v * g0);
    y[(size_t)s1 * DDIM + d] = __float2bfloat16(v * g1);
  }
}

// ======== fused in+swiglu grouped GEMM (single interleaved B), 128x128, BK=32 ========
// Verified R4/R5 structure + 1-D grid with bijective XCD chunking:
// L = (bid&7)*576 + bid>>3; consecutive L share (e, n-panel) -> B-slice L2 reuse per XCD.
__global__ __launch_bounds__(256, 3) void k_mlp1(
    const ushort* __restrict__ Abase, const ushort* __restrict__ Bbase,
    ushort* __restrict__ Obase, const int* __restrict__ d_cnt,
    const int* __restrict__ d_off) {
  constexpr int K = DDIM, NT = DDIM / 32;
  constexpr int BUF = 16384;
  __shared__ __align__(16) char smem[3 * BUF];
  int bid = blockIdx.x;
  int L = (bid & 7) * 576 + (bid >> 3);
  int e = L / 512;
  int rem = L - e * 512;
  int cnt = d_cnt[e];
  int m0 = (rem & 15) * 128;
  if (m0 >= cnt) return;
  int roff = d_off[e];
  int n0 = (rem >> 4) * 128;
  const ushort* B = Bbase + (size_t)e * NB1 * DDIM;
  int tid = threadIdx.x, w = tid >> 6, l = tid & 63;
  int wm = w >> 1, wn = w & 1, lr = l & 15, kg = l >> 4;
  size_t arow0 = (size_t)roff + m0;

  int srow = tid >> 2;
  int sgg = (tid & 3) ^ ((tid >> 3) & 3);
  const ushort* pA0 = Abase + (arow0 + srow) * (size_t)K + sgg * 8;
  const ushort* pA1 = pA0 + (size_t)64 * K;
  const ushort* pB0 = B + ((size_t)n0 + srow) * K + sgg * 8;
  const ushort* pB1 = pB0 + (size_t)64 * K;
  int tls = tid * 16;

  int xorg = (kg ^ ((lr >> 1) & 3)) << 4;
  int offA[4], offB[4];
#pragma unroll
  for (int i = 0; i < 4; i++) {
    offA[i] = (wm * 64 + i * 16 + lr) * 64 + xorg;
    offB[i] = 8192 + (wn * 64 + i * 16 + lr) * 64 + xorg;
  }

  f32x4 acc[4][4];
#pragma unroll
  for (int i = 0; i < 4; i++)
#pragma unroll
    for (int j = 0; j < 4; j++) acc[i][j] = {0.f, 0.f, 0.f, 0.f};

#pragma unroll
  for (int pt = 0; pt < 2; ++pt) {
    char* bb = smem + pt * BUF;
    lds16(pA0, bb + tls);         pA0 += 32;
    lds16(pA1, bb + 4096 + tls);  pA1 += 32;
    lds16(pB0, bb + 8192 + tls);  pB0 += 32;
    lds16(pB1, bb + 12288 + tls); pB1 += 32;
  }
  VMCNT(4);
  BARRIER();

  char* b0 = smem;
  char* b1 = smem + BUF;
  char* b2 = smem + 2 * BUF;
  for (int t = 0; t < NT; ++t) {
    bool st = (t + 2) < NT;
    short8v af[4], bf[4];
#pragma unroll
    for (int mf = 0; mf < 4; mf++) af[mf] = *(const short8v*)(b0 + offA[mf]);
#pragma unroll
    for (int nf = 0; nf < 2; nf++) bf[nf] = *(const short8v*)(b0 + offB[nf]);
    if (st) {
      lds16(pA0, b2 + tls);
      lds16(pA1, b2 + 4096 + tls);
    }
    pA0 += 32; pA1 += 32;
    BARRIER();
    __builtin_amdgcn_s_setprio(1);
#pragma unroll
    for (int nf = 0; nf < 2; nf++)
#pragma unroll
      for (int mf = 0; mf < 4; mf++)
        acc[mf][nf] = __builtin_amdgcn_mfma_f32_16x16x32_bf16(af[mf], bf[nf], acc[mf][nf], 0, 0, 0);
    __builtin_amdgcn_s_setprio(0);
    BARRIER();
#pragma unroll
    for (int nf = 2; nf < 4; nf++) bf[nf] = *(const short8v*)(b0 + offB[nf]);
    if (st) {
      lds16(pB0, b2 + 8192 + tls);
      lds16(pB1, b2 + 12288 + tls);
    }
    pB0 += 32; pB1 += 32;
    BARRIER();
    __builtin_amdgcn_s_setprio(1);
#pragma unroll
    for (int nf = 2; nf < 4; nf++)
#pragma unroll
      for (int mf = 0; mf < 4; mf++)
        acc[mf][nf] = __builtin_amdgcn_mfma_f32_16x16x32_bf16(af[mf], bf[nf], acc[mf][nf], 0, 0, 0);
    __builtin_amdgcn_s_setprio(0);
    if (t < NT - 1) {
      if (st) { VMCNT(4); } else { VMCNT(0); }
      BARRIER();
    }
    char* tmp = b0; b0 = b1; b1 = b2; b2 = tmp;
  }

  int j = (n0 >> 6) + wn;
#pragma unroll
  for (int mf = 0; mf < 4; mf++)
#pragma unroll
    for (int nf = 0; nf < 2; nf++)
#pragma unroll
      for (int r = 0; r < 4; r++) {
        int row = m0 + wm * 64 + mf * 16 + kg * 4 + r;
        if (row < cnt) {
          float mid = acc[mf][nf][r];
          float sw = acc[mf][nf + 2][r];
          float hv = mid * sigmoidf_(mid) * sw;
          int col = j * 32 + nf * 16 + lr;
          Obase[((size_t)roff + row) * FDIM + col] = f2bf(hv);
        }
      }
}

// ======== out-proj grouped GEMM, split-K=2, bf16 partials ========
__global__ __launch_bounds__(256, 3) void k_mlp2(
    const ushort* __restrict__ Abase, const ushort* __restrict__ Bbase,
    ushort* __restrict__ part, const int* __restrict__ d_cnt,
    const int* __restrict__ d_off) {
  constexpr int K = FDIM, NT = 1024 / 32;
  constexpr int BUF = 16384;
  __shared__ __align__(16) char smem[3 * BUF];
  int bid = blockIdx.x;
  int L = (bid & 7) * 288 + (bid >> 3);
  int e = L / 256;
  int rem = L - e * 256;
  int cnt = d_cnt[e];
  int sub = rem & 31;
  int mt = sub >> 1, kz = sub & 1;
  int m0 = mt * 128;
  if (m0 >= cnt) return;
  int roff = d_off[e];
  int n0 = (rem >> 5) * 128;
  int kbeg = kz * 1024;
  const ushort* B = Bbase + (size_t)e * DDIM * FDIM;
  int tid = threadIdx.x, w = tid >> 6, l = tid & 63;
  int wm = w >> 1, wn = w & 1, lr = l & 15, kg = l >> 4;
  size_t arow0 = (size_t)roff + m0;

  int srow = tid >> 2;
  int sgg = (tid & 3) ^ ((tid >> 3) & 3);
  const ushort* pA0 = Abase + (arow0 + srow) * (size_t)K + kbeg + sgg * 8;
  const ushort* pA1 = pA0 + (size_t)64 * K;
  const ushort* pB0 = B + ((size_t)n0 + srow) * K + kbeg + sgg * 8;
  const ushort* pB1 = pB0 + (size_t)64 * K;
  int tls = tid * 16;

  int xorg = (kg ^ ((lr >> 1) & 3)) << 4;
  int offA[4], offB[4];
#pragma unroll
  for (int i = 0; i < 4; i++) {
    offA[i] = (wm * 64 + i * 16 + lr) * 64 + xorg;
    offB[i] = 8192 + (wn * 64 + i * 16 + lr) * 64 + xorg;
  }

  f32x4 acc[4][4];
#pragma unroll
  for (int i = 0; i < 4; i++)
#pragma unroll
    for (int j = 0; j < 4; j++) acc[i][j] = {0.f, 0.f, 0.f, 0.f};

#pragma unroll
  for (int pt = 0; pt < 2; ++pt) {
    char* bb = smem + pt * BUF;
    lds16(pA0, bb + tls);         pA0 += 32;
    lds16(pA1, bb + 4096 + tls);  pA1 += 32;
    lds16(pB0, bb + 8192 + tls);  pB0 += 32;
    lds16(pB1, bb + 12288 + tls); pB1 += 32;
  }
  VMCNT(4);
  BARRIER();

  char* b0 = smem;
  char* b1 = smem + BUF;
  char* b2 = smem + 2 * BUF;
  for (int t = 0; t < NT; ++t) {
    bool st = (t + 2) < NT;
    short8v af[4], bf[4];
#pragma unroll
    for (int mf = 0; mf < 4; mf++) af[mf] = *(const short8v*)(b0 + offA[mf]);
#pragma unroll
    for (int nf = 0; nf < 2; nf++) bf[nf] = *(const short8v*)(b0 + offB[nf]);
    if (st) {
      lds16(pA0, b2 + tls);
      lds16(pA1, b2 + 4096 + tls);
    }
    pA0 += 32; pA1 += 32;
    BARRIER();
    __builtin_amdgcn_s_setprio(1);
#pragma unroll
    for (int nf = 0; nf < 2; nf++)
#pragma unroll
      for (int mf = 0; mf < 4; mf++)
        acc[mf][nf] = __builtin_amdgcn_mfma_f32_16x16x32_bf16(af[mf], bf[nf], acc[mf][nf], 0, 0, 0);
    __builtin_amdgcn_s_setprio(0);
    BARRIER();
#pragma unroll
    for (int nf = 2; nf < 4; nf++) bf[nf] = *(const short8v*)(b0 + offB[nf]);
    if (st) {
      lds16(pB0, b2 + 8192 + tls);
      lds16(pB1, b2 + 12288 + tls);
    }
    pB0 += 32; pB1 += 32;
    BARRIER();
    __builtin_amdgcn_s_setprio(1);
#pragma unroll
    for (int nf = 2; nf < 4; nf++)
#pragma unroll
      for (int mf = 0; mf < 4; mf++)
        acc[mf][nf] = __builtin_amdgcn_mfma_f32_16x16x32_bf16(af[mf], bf[nf], acc[mf][nf], 0, 0, 0);
    __builtin_amdgcn_s_setprio(0);
    if (t < NT - 1) {
      if (st) { VMCNT(4); } else { VMCNT(0); }
      BARRIER();
    }
    char* tmp = b0; b0 = b1; b1 = b2; b2 = tmp;
  }

  ushort* outp = part + (size_t)kz * SLOTS_T * DDIM;
#pragma unroll
  for (int mf = 0; mf < 4; mf++)
#pragma unroll
    for (int nf = 0; nf < 4; nf++)
#pragma unroll
      for (int r = 0; r < 4; r++) {
        int row = m0 + wm * 64 + mf * 16 + kg * 4 + r;
        if (row < cnt) {
          int col = n0 + wn * 64 + nf * 16 + lr;
          outp[((size_t)roff + row) * DDIM + col] = f2bf(acc[mf][nf][r]);
        }
      }
}

// ------- combine: out[t][d] = sum over {2 kz} x {s0, s1, shared row} of bf16 partials ----
__global__ void k_combine(const ushort* __restrict__ part, const int* __restrict__ slot_of,
                          float* __restrict__ out) {
  int t = blockIdx.x, q = threadIdx.x;
  int rows[3];
  rows[0] = slot_of[t * 2 + 0];
  rows[1] = slot_of[t * 2 + 1];
  rows[2] = SLOTS_R + t;
  size_t P = (size_t)SLOTS_T * DDIM;
  float o[4] = {0.f, 0.f, 0.f, 0.f};
#pragma unroll
  for (int kz = 0; kz < 2; kz++)
#pragma unroll
    for (int i = 0; i < 3; i++) {
      ushort4v v = *(const ushort4v*)(part + kz * P + (size_t)rows[i] * DDIM + q * 4);
#pragma unroll
      for (int j = 0; j < 4; j++) o[j] += bf2f(v[j]);
    }
  float4 ov = {o[0], o[1], o[2], o[3]};
  ((float4*)out)[(size_t)t * (DDIM / 4) + q] = ov;
}

extern "C" void kernel_launch(void* const* d_in, const int* in_sizes, int n_in,
                              void* d_out, int out_size, void* d_ws, size_t ws_size,
                              hipStream_t stream) {
  (void)in_sizes; (void)n_in; (void)out_size; (void)ws_size;
  const float* x        = (const float*)d_in[0];
  const float* router   = (const float*)d_in[1];
  const float* w_in_sh  = (const float*)d_in[2];
  const float* w_out_sh = (const float*)d_in[3];
  const float* w_sw_sh  = (const float*)d_in[4];
  const float* w_in_e   = (const float*)d_in[5];
  const float* w_sw_e   = (const float*)d_in[6];
  const float* w_out_e  = (const float*)d_in[7];
  float* out = (float*)d_out;

  char* ws = (char*)d_ws;
  size_t off = 0;
  auto alloc = [&](size_t bytes) -> char* {
    char* p = ws + off;
    off += (bytes + 255) & ~(size_t)255;
    return p;
  };
  // Ordering: y_all ++ xbf ++ h contiguous (A-matrix of 6144 rows; overreads in-bounds).
  // part aliases wt12 (dead after k_mlp1; k_mlp2 reads wt_out_t + h only).
  ushort* wt12     = (ushort*)alloc((size_t)NE9 * NB1 * DDIM * 2);   // 75.5 MB
  ushort* wt_out_t = (ushort*)alloc((size_t)NE9 * DDIM * FDIM * 2);  // 37.7 MB
  __hip_bfloat16* y_all = (__hip_bfloat16*)alloc((size_t)SLOTS_R * DDIM * 2);
  __hip_bfloat16* xbf   = (__hip_bfloat16*)alloc((size_t)A_TOK * DDIM * 2);
  ushort* h        = (ushort*)alloc((size_t)SLOTS_T * FDIM * 2);     // 25.2 MB
  int*   counts  = (int*)alloc(64);
  int*   offs    = (int*)alloc(64);
  int*   cursor  = (int*)alloc(64);
  int*   ticket  = (int*)alloc(64);
  int*   top_e   = (int*)alloc((size_t)A_TOK * 2 * 4);
  float* top_g   = (float*)alloc((size_t)A_TOK * 2 * 4);
  int*   slot_of = (int*)alloc((size_t)A_TOK * 2 * 4);
  (void)alloc(1 << 20);  // guard for mlp2 A-tile overread
  ushort* part = wt12;   // [2][6144][1024] bf16 = 25.2 MB alias

  // 1) weight prep + counts/ticket zeroing (one launch)
  k_prep<<<dim3(PREP_NWG), 256, 0, stream>>>(
      w_in_e, w_sw_e, w_out_e, w_in_sh, w_sw_sh, w_out_sh,
      wt12, wt_out_t, counts, ticket);

  // 2) router (+ fused scan in last block)
  k_router<<<dim3(A_TOK / 4), 256, 0, stream>>>(x, router, xbf, counts, top_e, top_g,
                                                offs, cursor, ticket);

  // 3) dispatch
  k_dispatch<<<dim3(A_TOK / 4), 256, 0, stream>>>(x, top_e, top_g, offs, cursor, slot_of, y_all);

  // 4) fused in+swiglu (1-D grid, XCD-chunked)
  k_mlp1<<<dim3(32 * 16 * NE9), 256, 0, stream>>>(
      (const ushort*)y_all, wt12, h, counts, offs);

  // 5) out-proj, split-K=2 (1-D grid, XCD-chunked)
  k_mlp2<<<dim3(8 * 32 * NE9), 256, 0, stream>>>(
      h, wt_out_t, part, counts, offs);

  // 6) combine (fully overwrites d_out -> poison-safe)
  k_combine<<<dim3(A_TOK), 256, 0, stream>>>(part, slot_of, out);
}

// Round 7
// 310.748 us; speedup vs baseline: 1.3146x; 1.3146x over previous
//
#include <hip/hip_runtime.h>
#include <hip/hip_bf16.h>

#define A_TOK 2048
#define DDIM 1024
#define FDIM 2048
#define NEXP 8
#define NE9 9                      // 8 routed + 1 shared pseudo-expert
#define SLOTS_R (2 * A_TOK)        // 4096 routed slots
#define SLOTS_T (SLOTS_R + A_TOK)  // 6144 incl. shared rows
#define NB1 (2 * FDIM)             // 4096 virtual interleaved [w_in|w_swiglu] cols (32-blocks)

typedef __attribute__((ext_vector_type(8))) short short8v;   // 8 bf16
typedef __attribute__((ext_vector_type(4))) float f32x4;
typedef __attribute__((ext_vector_type(4))) ushort ushort4v;

#define BARRIER() asm volatile("s_barrier" ::: "memory")
#define VMCNT0() asm volatile("s_waitcnt vmcnt(0)" ::: "memory")
#define LGKM0() asm volatile("s_waitcnt lgkmcnt(0)" ::: "memory")

__device__ __forceinline__ void lds16(const void* g, void* l) {
  __builtin_amdgcn_global_load_lds((const __attribute__((address_space(1))) void*)g,
                                   (__attribute__((address_space(3))) void*)l, 16, 0, 0);
}

__device__ __forceinline__ float sigmoidf_(float x) { return 1.f / (1.f + __expf(-x)); }
__device__ __forceinline__ ushort f2bf(float x) {
  __hip_bfloat16 b = __float2bfloat16(x);
  ushort u; __builtin_memcpy(&u, &b, 2); return u;
}
__device__ __forceinline__ float bf2f(ushort u) {
  union { unsigned int i; float f; } x; x.i = (unsigned int)u << 16; return x.f;
}
__device__ __forceinline__ unsigned pk2(float a, float b) {
  return (unsigned)f2bf(a) | ((unsigned)f2bf(b) << 16);
}

// ---------------- router ----------------
__global__ void k_router(const float* __restrict__ x, const float* __restrict__ rw,
                         __hip_bfloat16* __restrict__ xbf, int* __restrict__ counts,
                         int* __restrict__ top_e, float* __restrict__ top_g) {
  int t = blockIdx.x * 4 + (threadIdx.x >> 6);
  int l = threadIdx.x & 63;
  const float* xr = x + (size_t)t * DDIM;
  float acc[NEXP];
#pragma unroll
  for (int e = 0; e < NEXP; e++) acc[e] = 0.f;
#pragma unroll
  for (int i = 0; i < 16; i++) {
    int d = i * 64 + l;
    float v = xr[d];
    xbf[(size_t)t * DDIM + d] = __float2bfloat16(v);
    const float* rr = rw + (size_t)d * NEXP;
#pragma unroll
    for (int e = 0; e < NEXP; e++) acc[e] += v * rr[e];
  }
#pragma unroll
  for (int e = 0; e < NEXP; e++) {
#pragma unroll
    for (int s = 32; s > 0; s >>= 1) acc[e] += __shfl_xor(acc[e], s);
  }
  if (l == 0) {
    float b1 = -1e30f, b2 = -1e30f;
    int i1 = 0, i2 = 0;
#pragma unroll
    for (int e = 0; e < NEXP; e++) {
      float v = acc[e];
      if (v > b1) { b2 = b1; i2 = i1; b1 = v; i1 = e; }
      else if (v > b2) { b2 = v; i2 = e; }
    }
    atomicAdd(&counts[i1], 1);
    atomicAdd(&counts[i2], 1);
    top_e[t * 2 + 0] = i1; top_e[t * 2 + 1] = i2;
    top_g[t * 2 + 0] = sigmoidf_(b1); top_g[t * 2 + 1] = sigmoidf_(b2);
  }
}

__global__ void k_scan(int* __restrict__ counts, int* __restrict__ offs,
                       int* __restrict__ cursor) {
  if (threadIdx.x == 0 && blockIdx.x == 0) {
    counts[NEXP] = A_TOK;  // shared pseudo-expert
    int s = 0;
    for (int e = 0; e < NE9; e++) { offs[e] = s; s += counts[e]; cursor[e] = 0; }
  }
}

__global__ void k_dispatch(const float* __restrict__ x, const int* __restrict__ top_e,
                           const float* __restrict__ top_g, const int* __restrict__ offs,
                           int* __restrict__ cursor, int* __restrict__ slot_of,
                           __hip_bfloat16* __restrict__ y) {
  int t = blockIdx.x * 4 + (threadIdx.x >> 6);
  int l = threadIdx.x & 63;
  int e0 = top_e[t * 2 + 0], e1 = top_e[t * 2 + 1];
  float g0 = top_g[t * 2 + 0], g1 = top_g[t * 2 + 1];
  int s0 = 0, s1 = 0;
  if (l == 0) {
    s0 = offs[e0] + atomicAdd(&cursor[e0], 1);
    s1 = offs[e1] + atomicAdd(&cursor[e1], 1);
    slot_of[t * 2 + 0] = s0; slot_of[t * 2 + 1] = s1;
  }
  s0 = __shfl(s0, 0); s1 = __shfl(s1, 0);
  const float* xr = x + (size_t)t * DDIM;
#pragma unroll
  for (int i = 0; i < 16; i++) {
    int d = i * 64 + l;
    float v = xr[d];
    y[(size_t)s0 * DDIM + d] = __float2bfloat16(v * g0);
    y[(size_t)s1 * DDIM + d] = __float2bfloat16(v * g1);
  }
}

// ======== fused in+swiglu grouped GEMM, B = ORIGINAL fp32 weights ========
// A: bf16 [6144][1024] (y_all++xbf), staged via gload_lds (2-buf, swizzled source).
// B: virtual interleaved [4096][1024]: col n' -> which=(n'>>5)&1, f=(n'>>6)*32+(n'&31);
//    reg-staged from fp32 w_in_e/w_sw_e [e][D][F] (transpose in regs) or shared
//    w_in_sh/w_sw_sh [F][D] (direct), cvt to bf16, ds_write_b64 with XOR swizzle.
// 2-buf classic: issue(t+1) early, MFMA(t), vmcnt(0), write B(t+1), lgkm0, barrier.
__global__ __launch_bounds__(256, 3) void k_mlp1(
    const ushort* __restrict__ Abase, const float* __restrict__ w_in_e,
    const float* __restrict__ w_sw_e, const float* __restrict__ w_in_sh,
    const float* __restrict__ w_sw_sh, ushort* __restrict__ Obase,
    const int* __restrict__ d_cnt, const int* __restrict__ d_off) {
  constexpr int NT = 32;  // K=1024 / BK=32
  __shared__ __align__(16) char smem[32768];  // A0 A1 | B0 B1 (8KB each)
  int e = blockIdx.z;
  int cnt = d_cnt[e];
  int m0 = blockIdx.y * 128;
  if (m0 >= cnt) return;
  int roff = d_off[e];
  int n0b = blockIdx.x * 128;
  int tid = threadIdx.x, w = tid >> 6, l = tid & 63;
  int wm = w >> 1, wn = w & 1, lr = l & 15, kg = l >> 4;
  size_t arow0 = (size_t)roff + m0;

  // A staging (bf16 gload_lds, pre-swizzled source granule)
  int srow = tid >> 2;
  int sgg = (tid & 3) ^ ((tid >> 3) & 3);
  const ushort* pA0 = Abase + (arow0 + srow) * (size_t)DDIM + sgg * 8;
  const ushort* pA1 = pA0 + (size_t)64 * DDIM;
  int tls = tid * 16;

  // B staging (fp32 reg-staged): thread covers 4k x 4n
  int kq = tid >> 5, nq = tid & 31;
  int nl0 = nq * 4;
  int nprime = n0b + nl0;
  int which = (nprime >> 5) & 1;
  bool shared_e = (e == NEXP);
  const float* pB;
  size_t bst;   // element stride between the 4 loads
  int badv;     // pB advance per K-tile (elements)
  if (!shared_e) {
    int f0 = ((nprime >> 6) << 5) + (nprime & 31);
    const float* wb = which ? w_sw_e : w_in_e;
    pB = wb + (size_t)e * DDIM * FDIM + (size_t)(kq * 4) * FDIM + f0;
    bst = FDIM; badv = 32 * FDIM;   // loads walk k-rows; float4 over f(n) -> transpose
  } else {
    int f0 = ((nprime >> 6) << 5) + (nprime & 31);
    const float* wb = which ? w_sw_sh : w_in_sh;
    pB = wb + (size_t)f0 * DDIM + kq * 4;
    bst = DDIM; badv = 32;          // loads walk n(f)-rows; float4 over k -> direct
  }
  int wofs[4];
#pragma unroll
  for (int j = 0; j < 4; j++) {
    int nloc = nl0 + j;
    wofs[j] = nloc * 64 + ((((kq >> 1) ^ ((nloc >> 1) & 3)) << 4) | ((kq & 1) << 3));
  }

  // frag LDS byte offsets (xor term verified R4/R5)
  int xorg = (kg ^ ((lr >> 1) & 3)) << 4;
  int offA[4], offB[4];
#pragma unroll
  for (int i = 0; i < 4; i++) {
    offA[i] = (wm * 64 + i * 16 + lr) * 64 + xorg;
    offB[i] = (wn * 64 + i * 16 + lr) * 64 + xorg;
  }

  f32x4 acc[4][4];
#pragma unroll
  for (int i = 0; i < 4; i++)
#pragma unroll
    for (int j = 0; j < 4; j++) acc[i][j] = {0.f, 0.f, 0.f, 0.f};

  char* bufA0 = smem;
  char* bufA1 = smem + 8192;
  char* bufB0 = smem + 16384;
  char* bufB1 = smem + 24576;

  float4 rb0, rb1, rb2, rb3;
  auto loadB = [&]() {
    rb0 = *(const float4*)(pB);
    rb1 = *(const float4*)(pB + bst);
    rb2 = *(const float4*)(pB + 2 * bst);
    rb3 = *(const float4*)(pB + 3 * bst);
    pB += badv;
  };
  auto writeB = [&](char* bb) {
    uint2 w0, w1, w2, w3;
    if (!shared_e) {  // regs are k-major: row j takes component j of each load
      w0 = {pk2(rb0.x, rb1.x), pk2(rb2.x, rb3.x)};
      w1 = {pk2(rb0.y, rb1.y), pk2(rb2.y, rb3.y)};
      w2 = {pk2(rb0.z, rb1.z), pk2(rb2.z, rb3.z)};
      w3 = {pk2(rb0.w, rb1.w), pk2(rb2.w, rb3.w)};
    } else {          // regs are n-major: row j = load j
      w0 = {pk2(rb0.x, rb0.y), pk2(rb0.z, rb0.w)};
      w1 = {pk2(rb1.x, rb1.y), pk2(rb1.z, rb1.w)};
      w2 = {pk2(rb2.x, rb2.y), pk2(rb2.z, rb2.w)};
      w3 = {pk2(rb3.x, rb3.y), pk2(rb3.z, rb3.w)};
    }
    *(uint2*)(bb + wofs[0]) = w0;
    *(uint2*)(bb + wofs[1]) = w1;
    *(uint2*)(bb + wofs[2]) = w2;
    *(uint2*)(bb + wofs[3]) = w3;
  };

  // prologue: tile 0
  loadB();
  lds16(pA0, bufA0 + tls); lds16(pA1, bufA0 + 4096 + tls);
  pA0 += 32; pA1 += 32;
  VMCNT0();
  writeB(bufB0);
  LGKM0();
  BARRIER();

  char* cA = bufA0; char* nA = bufA1;
  char* cB = bufB0; char* nB = bufB1;
  for (int t = 0; t < NT; ++t) {
    bool stg = (t + 1) < NT;
    if (stg) {
      loadB();  // B(t+1) -> regs
      lds16(pA0, nA + tls); lds16(pA1, nA + 4096 + tls);
      pA0 += 32; pA1 += 32;
    }
    short8v af[4], bf[4];
#pragma unroll
    for (int i = 0; i < 4; i++) af[i] = *(const short8v*)(cA + offA[i]);
#pragma unroll
    for (int i = 0; i < 4; i++) bf[i] = *(const short8v*)(cB + offB[i]);
    __builtin_amdgcn_s_setprio(1);
#pragma unroll
    for (int nf = 0; nf < 4; nf++)
#pragma unroll
      for (int mf = 0; mf < 4; mf++)
        acc[mf][nf] = __builtin_amdgcn_mfma_f32_16x16x32_bf16(af[mf], bf[nf], acc[mf][nf], 0, 0, 0);
    __builtin_amdgcn_s_setprio(0);
    if (stg) {
      VMCNT0();       // A(t+1) landed in LDS; B(t+1) regs arrived
      writeB(nB);
      LGKM0();
      BARRIER();
      char* tp = cA; cA = nA; nA = tp;
      tp = cB; cB = nB; nB = tp;
    }
  }

  // epilogue: nf0,1 = mid, nf2,3 = sw of the SAME h-col (virtual interleave)
  int j = (n0b >> 6) + wn;
#pragma unroll
  for (int mf = 0; mf < 4; mf++)
#pragma unroll
    for (int nf = 0; nf < 2; nf++)
#pragma unroll
      for (int r = 0; r < 4; r++) {
        int row = m0 + wm * 64 + mf * 16 + kg * 4 + r;
        if (row < cnt) {
          float mid = acc[mf][nf][r];
          float sw = acc[mf][nf + 2][r];
          float hv = mid * sigmoidf_(mid) * sw;
          int col = j * 32 + nf * 16 + lr;
          Obase[((size_t)roff + row) * FDIM + col] = f2bf(hv);
        }
      }
}

// ======== out-proj grouped GEMM, split-K=2, B = ORIGINAL fp32 w_out ========
// A: bf16 [6144][2048] (h). B: routed w_out_e [e][F][D] (k-rows -> transpose) or
// shared w_out_sh [D][F] (n-rows -> direct). part: bf16 [2][6144][1024].
__global__ __launch_bounds__(256, 3) void k_mlp2(
    const ushort* __restrict__ Abase, const float* __restrict__ w_out_e,
    const float* __restrict__ w_out_sh, ushort* __restrict__ part,
    const int* __restrict__ d_cnt, const int* __restrict__ d_off) {
  constexpr int NT = 32;  // 1024 K per split / 32
  __shared__ __align__(16) char smem[32768];
  int e = blockIdx.z;
  int cnt = d_cnt[e];
  int mt = blockIdx.y >> 1, kz = blockIdx.y & 1;
  int m0 = mt * 128;
  if (m0 >= cnt) return;
  int roff = d_off[e];
  int n0b = blockIdx.x * 128;
  int kbeg = kz * 1024;
  int tid = threadIdx.x, w = tid >> 6, l = tid & 63;
  int wm = w >> 1, wn = w & 1, lr = l & 15, kg = l >> 4;
  size_t arow0 = (size_t)roff + m0;

  int srow = tid >> 2;
  int sgg = (tid & 3) ^ ((tid >> 3) & 3);
  const ushort* pA0 = Abase + (arow0 + srow) * (size_t)FDIM + kbeg + sgg * 8;
  const ushort* pA1 = pA0 + (size_t)64 * FDIM;
  int tls = tid * 16;

  int kq = tid >> 5, nq = tid & 31;
  int nl0 = nq * 4;
  int nprime = n0b + nl0;
  bool shared_e = (e == NEXP);
  const float* pB;
  size_t bst;
  int badv;
  if (!shared_e) {
    pB = w_out_e + (size_t)e * FDIM * DDIM + (size_t)(kbeg + kq * 4) * DDIM + nprime;
    bst = DDIM; badv = 32 * DDIM;
  } else {
    pB = w_out_sh + (size_t)nprime * FDIM + kbeg + kq * 4;
    bst = FDIM; badv = 32;
  }
  int wofs[4];
#pragma unroll
  for (int j = 0; j < 4; j++) {
    int nloc = nl0 + j;
    wofs[j] = nloc * 64 + ((((kq >> 1) ^ ((nloc >> 1) & 3)) << 4) | ((kq & 1) << 3));
  }

  int xorg = (kg ^ ((lr >> 1) & 3)) << 4;
  int offA[4], offB[4];
#pragma unroll
  for (int i = 0; i < 4; i++) {
    offA[i] = (wm * 64 + i * 16 + lr) * 64 + xorg;
    offB[i] = (wn * 64 + i * 16 + lr) * 64 + xorg;
  }

  f32x4 acc[4][4];
#pragma unroll
  for (int i = 0; i < 4; i++)
#pragma unroll
    for (int j = 0; j < 4; j++) acc[i][j] = {0.f, 0.f, 0.f, 0.f};

  char* bufA0 = smem;
  char* bufA1 = smem + 8192;
  char* bufB0 = smem + 16384;
  char* bufB1 = smem + 24576;

  float4 rb0, rb1, rb2, rb3;
  auto loadB = [&]() {
    rb0 = *(const float4*)(pB);
    rb1 = *(const float4*)(pB + bst);
    rb2 = *(const float4*)(pB + 2 * bst);
    rb3 = *(const float4*)(pB + 3 * bst);
    pB += badv;
  };
  auto writeB = [&](char* bb) {
    uint2 w0, w1, w2, w3;
    if (!shared_e) {
      w0 = {pk2(rb0.x, rb1.x), pk2(rb2.x, rb3.x)};
      w1 = {pk2(rb0.y, rb1.y), pk2(rb2.y, rb3.y)};
      w2 = {pk2(rb0.z, rb1.z), pk2(rb2.z, rb3.z)};
      w3 = {pk2(rb0.w, rb1.w), pk2(rb2.w, rb3.w)};
    } else {
      w0 = {pk2(rb0.x, rb0.y), pk2(rb0.z, rb0.w)};
      w1 = {pk2(rb1.x, rb1.y), pk2(rb1.z, rb1.w)};
      w2 = {pk2(rb2.x, rb2.y), pk2(rb2.z, rb2.w)};
      w3 = {pk2(rb3.x, rb3.y), pk2(rb3.z, rb3.w)};
    }
    *(uint2*)(bb + wofs[0]) = w0;
    *(uint2*)(bb + wofs[1]) = w1;
    *(uint2*)(bb + wofs[2]) = w2;
    *(uint2*)(bb + wofs[3]) = w3;
  };

  loadB();
  lds16(pA0, bufA0 + tls); lds16(pA1, bufA0 + 4096 + tls);
  pA0 += 32; pA1 += 32;
  VMCNT0();
  writeB(bufB0);
  LGKM0();
  BARRIER();

  char* cA = bufA0; char* nA = bufA1;
  char* cB = bufB0; char* nB = bufB1;
  for (int t = 0; t < NT; ++t) {
    bool stg = (t + 1) < NT;
    if (stg) {
      loadB();
      lds16(pA0, nA + tls); lds16(pA1, nA + 4096 + tls);
      pA0 += 32; pA1 += 32;
    }
    short8v af[4], bf[4];
#pragma unroll
    for (int i = 0; i < 4; i++) af[i] = *(const short8v*)(cA + offA[i]);
#pragma unroll
    for (int i = 0; i < 4; i++) bf[i] = *(const short8v*)(cB + offB[i]);
    __builtin_amdgcn_s_setprio(1);
#pragma unroll
    for (int nf = 0; nf < 4; nf++)
#pragma unroll
      for (int mf = 0; mf < 4; mf++)
        acc[mf][nf] = __builtin_amdgcn_mfma_f32_16x16x32_bf16(af[mf], bf[nf], acc[mf][nf], 0, 0, 0);
    __builtin_amdgcn_s_setprio(0);
    if (stg) {
      VMCNT0();
      writeB(nB);
      LGKM0();
      BARRIER();
      char* tp = cA; cA = nA; nA = tp;
      tp = cB; cB = nB; nB = tp;
    }
  }

  ushort* outp = part + (size_t)kz * SLOTS_T * DDIM;
#pragma unroll
  for (int mf = 0; mf < 4; mf++)
#pragma unroll
    for (int nf = 0; nf < 4; nf++)
#pragma unroll
      for (int r = 0; r < 4; r++) {
        int row = m0 + wm * 64 + mf * 16 + kg * 4 + r;
        if (row < cnt) {
          int col = n0b + wn * 64 + nf * 16 + lr;
          outp[((size_t)roff + row) * DDIM + col] = f2bf(acc[mf][nf][r]);
        }
      }
}

// ------- combine: out[t][d] = sum over {2 kz} x {s0, s1, shared row} of bf16 partials ----
__global__ void k_combine(const ushort* __restrict__ part, const int* __restrict__ slot_of,
                          float* __restrict__ out) {
  int t = blockIdx.x, q = threadIdx.x;
  int rows[3];
  rows[0] = slot_of[t * 2 + 0];
  rows[1] = slot_of[t * 2 + 1];
  rows[2] = SLOTS_R + t;
  size_t P = (size_t)SLOTS_T * DDIM;
  float o[4] = {0.f, 0.f, 0.f, 0.f};
#pragma unroll
  for (int kz = 0; kz < 2; kz++)
#pragma unroll
    for (int i = 0; i < 3; i++) {
      ushort4v v = *(const ushort4v*)(part + kz * P + (size_t)rows[i] * DDIM + q * 4);
#pragma unroll
      for (int j = 0; j < 4; j++) o[j] += bf2f(v[j]);
    }
  float4 ov = {o[0], o[1], o[2], o[3]};
  ((float4*)out)[(size_t)t * (DDIM / 4) + q] = ov;
}

extern "C" void kernel_launch(void* const* d_in, const int* in_sizes, int n_in,
                              void* d_out, int out_size, void* d_ws, size_t ws_size,
                              hipStream_t stream) {
  (void)in_sizes; (void)n_in; (void)out_size; (void)ws_size;
  const float* x        = (const float*)d_in[0];
  const float* router   = (const float*)d_in[1];
  const float* w_in_sh  = (const float*)d_in[2];
  const float* w_out_sh = (const float*)d_in[3];
  const float* w_sw_sh  = (const float*)d_in[4];
  const float* w_in_e   = (const float*)d_in[5];
  const float* w_sw_e   = (const float*)d_in[6];
  const float* w_out_e  = (const float*)d_in[7];
  float* out = (float*)d_out;

  char* ws = (char*)d_ws;
  size_t off = 0;
  auto alloc = [&](size_t bytes) -> char* {
    char* p = ws + off;
    off += (bytes + 255) & ~(size_t)255;
    return p;
  };
  // y_all ++ xbf ++ h contiguous: A-row overreads (count-guarded stores) stay in-bounds.
  __hip_bfloat16* y_all = (__hip_bfloat16*)alloc((size_t)SLOTS_R * DDIM * 2);
  __hip_bfloat16* xbf   = (__hip_bfloat16*)alloc((size_t)A_TOK * DDIM * 2);
  ushort* h    = (ushort*)alloc((size_t)SLOTS_T * FDIM * 2);     // 25.2 MB
  ushort* part = (ushort*)alloc((size_t)2 * SLOTS_T * DDIM * 2); // 25.2 MB
  int*   counts  = (int*)alloc(64);
  int*   offs    = (int*)alloc(64);
  int*   cursor  = (int*)alloc(64);
  int*   top_e   = (int*)alloc((size_t)A_TOK * 2 * 4);
  float* top_g   = (float*)alloc((size_t)A_TOK * 2 * 4);
  int*   slot_of = (int*)alloc((size_t)A_TOK * 2 * 4);
  (void)alloc(1 << 20);  // guard

  hipMemsetAsync(counts, 0, 64, stream);

  // routing
  k_router<<<dim3(A_TOK / 4), 256, 0, stream>>>(x, router, xbf, counts, top_e, top_g);
  k_scan<<<1, 64, 0, stream>>>(counts, offs, cursor);
  k_dispatch<<<dim3(A_TOK / 4), 256, 0, stream>>>(x, top_e, top_g, offs, cursor, slot_of, y_all);

  // fused in+swiglu: B consumed directly from fp32 weights (no prep)
  k_mlp1<<<dim3(NB1 / 128, A_TOK / 128, NE9), 256, 0, stream>>>(
      (const ushort*)y_all, w_in_e, w_sw_e, w_in_sh, w_sw_sh, h, counts, offs);

  // out-proj, split-K=2: B directly from fp32 w_out
  k_mlp2<<<dim3(DDIM / 128, (A_TOK / 128) * 2, NE9), 256, 0, stream>>>(
      h, w_out_e, w_out_sh, part, counts, offs);

  // combine (fully overwrites d_out -> poison-safe)
  k_combine<<<dim3(A_TOK), 256, 0, stream>>>(part, slot_of, out);
}

// Round 8
// 251.200 us; speedup vs baseline: 1.6262x; 1.2371x over previous
//
#include <hip/hip_runtime.h>
#include <hip/hip_bf16.h>

#define A_TOK 2048
#define DDIM 1024
#define FDIM 2048
#define NEXP 8
#define NE9 9                      // 8 routed + 1 shared pseudo-expert
#define SLOTS_R (2 * A_TOK)        // 4096 routed slots
#define SLOTS_T (SLOTS_R + A_TOK)  // 6144 incl. shared rows
#define NB1 (2 * FDIM)             // 4096: interleaved [w_in | w_swiglu] rows (32-col blocks)

// k_prep job ranges (flat 1-D grid)
#define PREP_TRA_END 8192                     // 16 z * 512 tiles
#define PREP_TRB_END (PREP_TRA_END + 4096)    // 8 z * 512 tiles
#define PREP_SH12_END (PREP_TRB_END + 1024)   // 4096 row-jobs / 4
#define PREP_SHOUT_END (PREP_SH12_END + 512)  // 1024 rows / 2
#define PREP_NWG (PREP_SHOUT_END + 512)       // + router jobs (2048 tokens / 4)

typedef __attribute__((ext_vector_type(8))) short short8v;   // 8 bf16
typedef __attribute__((ext_vector_type(4))) float f32x4;
typedef __attribute__((ext_vector_type(4))) ushort ushort4v;

#define BARRIER() asm volatile("s_barrier" ::: "memory")
#define VMCNT(n) asm volatile("s_waitcnt vmcnt(" #n ")" ::: "memory")

__device__ __forceinline__ void lds16(const void* g, void* l) {
  __builtin_amdgcn_global_load_lds((const __attribute__((address_space(1))) void*)g,
                                   (__attribute__((address_space(3))) void*)l, 16, 0, 0);
}

__device__ __forceinline__ float sigmoidf_(float x) { return 1.f / (1.f + __expf(-x)); }
__device__ __forceinline__ ushort f2bf(float x) {
  __hip_bfloat16 b = __float2bfloat16(x);
  ushort u; __builtin_memcpy(&u, &b, 2); return u;
}
__device__ __forceinline__ float bf2f(ushort u) {
  union { unsigned int i; float f; } x; x.i = (unsigned int)u << 16; return x.f;
}

// ============== consolidated prep: weight convert/transpose + router (one launch) ==============
__global__ void k_prep(const float* __restrict__ w_in_e, const float* __restrict__ w_sw_e,
                       const float* __restrict__ w_out_e, const float* __restrict__ w_in_sh,
                       const float* __restrict__ w_sw_sh, const float* __restrict__ w_out_sh,
                       ushort* __restrict__ wt12, ushort* __restrict__ wt_out_t,
                       const float* __restrict__ x, const float* __restrict__ rw,
                       __hip_bfloat16* __restrict__ xbf, int* __restrict__ top_e,
                       float* __restrict__ top_g) {
  __shared__ ushort tile[64][68];
  int b = blockIdx.x, tid = threadIdx.x;
  if (b < PREP_TRA_END) {
    // trA: w_in_e/w_sw_e [e][D][F] fp32 -> wt12[e][4096][1024] bf16 (interleaved remap)
    int z = b >> 9, t2 = b & 511;
    int e = z & 7, which = z >> 3;
    const float* in = (which ? w_sw_e : w_in_e) + (size_t)e * DDIM * FDIM;
    ushort* outb = wt12 + (size_t)e * NB1 * DDIM;
    int c0 = (t2 & 31) * 64, r0 = (t2 >> 5) * 64;   // c over F, r over D
    int rr = tid >> 4, cq = tid & 15;
#pragma unroll
    for (int i = 0; i < 4; i++) {
      int r = i * 16 + rr;
      float4 v = *(const float4*)(in + (size_t)(r0 + r) * FDIM + c0 + cq * 4);
      ushort4v o = {f2bf(v.x), f2bf(v.y), f2bf(v.z), f2bf(v.w)};
      *(ushort4v*)&tile[r][cq * 4] = o;
    }
    __syncthreads();
    int cc = tid >> 4, rq = tid & 15;
#pragma unroll
    for (int i = 0; i < 4; i++) {
      int c = i * 16 + cc;
      int f = c0 + c;
      int rp = ((f >> 5) << 6) + (which << 5) + (f & 31);
      ushort4v o = {tile[rq * 4 + 0][c], tile[rq * 4 + 1][c],
                    tile[rq * 4 + 2][c], tile[rq * 4 + 3][c]};
      *(ushort4v*)(outb + (size_t)rp * DDIM + r0 + rq * 4) = o;
    }
  } else if (b < PREP_TRB_END) {
    // trB: w_out_e [e][F][D] fp32 -> wt_out_t [e][D][F] bf16 (plain transpose)
    int b2 = b - PREP_TRA_END;
    int z = b2 >> 9, t2 = b2 & 511;
    const float* in = w_out_e + (size_t)z * FDIM * DDIM;
    ushort* out = wt_out_t + (size_t)z * DDIM * FDIM;
    int c0 = (t2 & 15) * 64, r0 = (t2 >> 4) * 64;   // c over D, r over F
    int rr = tid >> 4, cq = tid & 15;
#pragma unroll
    for (int i = 0; i < 4; i++) {
      int r = i * 16 + rr;
      float4 v = *(const float4*)(in + (size_t)(r0 + r) * DDIM + c0 + cq * 4);
      ushort4v o = {f2bf(v.x), f2bf(v.y), f2bf(v.z), f2bf(v.w)};
      *(ushort4v*)&tile[r][cq * 4] = o;
    }
    __syncthreads();
    int cc = tid >> 4, rq = tid & 15;
#pragma unroll
    for (int i = 0; i < 4; i++) {
      int c = i * 16 + cc;
      ushort4v o = {tile[rq * 4 + 0][c], tile[rq * 4 + 1][c],
                    tile[rq * 4 + 2][c], tile[rq * 4 + 3][c]};
      *(ushort4v*)(out + (size_t)(c0 + c) * FDIM + r0 + rq * 4) = o;
    }
  } else if (b < PREP_SH12_END) {
    // shared in/sw [F][D] -> wt12[8] rows (remap; already K-contiguous)
    int j = b - PREP_TRB_END;
    int rj = j * 4 + (tid >> 6);   // 0..4095
    int l = tid & 63;
    int which = rj & 1, f = rj >> 1;
    const float* src = (which ? w_sw_sh : w_in_sh) + (size_t)f * DDIM;
    int rp = ((f >> 5) << 6) + (which << 5) + (f & 31);
    ushort* dst = wt12 + (size_t)NEXP * NB1 * DDIM + (size_t)rp * DDIM;
#pragma unroll
    for (int i = 0; i < 4; i++) {
      int q = l + 64 * i;
      float4 v = ((const float4*)src)[q];
      ushort4v o = {f2bf(v.x), f2bf(v.y), f2bf(v.z), f2bf(v.w)};
      ((ushort4v*)dst)[q] = o;
    }
  } else if (b < PREP_SHOUT_END) {
    // shared out [D][F] -> wt_out_t[8] rows (plain convert)
    int j = b - PREP_SH12_END;
    int d = j * 2 + (tid >> 7);    // 0..1023
    int l = tid & 127;
    const float* src = w_out_sh + (size_t)d * FDIM;
    ushort* dst = wt_out_t + (size_t)NEXP * DDIM * FDIM + (size_t)d * FDIM;
#pragma unroll
    for (int i = 0; i < 4; i++) {
      int q = l + 128 * i;
      float4 v = ((const float4*)src)[q];
      ushort4v o = {f2bf(v.x), f2bf(v.y), f2bf(v.z), f2bf(v.w)};
      ((ushort4v*)dst)[q] = o;
    }
  } else {
    // router (write-only: no atomics, no pre-zeroed state)
    int j = b - PREP_SHOUT_END;
    int t = j * 4 + (tid >> 6);
    int l = tid & 63;
    const float* xr = x + (size_t)t * DDIM;
    float acc[NEXP];
#pragma unroll
    for (int e = 0; e < NEXP; e++) acc[e] = 0.f;
#pragma unroll
    for (int i = 0; i < 16; i++) {
      int d = i * 64 + l;
      float v = xr[d];
      xbf[(size_t)t * DDIM + d] = __float2bfloat16(v);
      const float* rr = rw + (size_t)d * NEXP;
#pragma unroll
      for (int e = 0; e < NEXP; e++) acc[e] += v * rr[e];
    }
#pragma unroll
    for (int e = 0; e < NEXP; e++) {
#pragma unroll
      for (int s = 32; s > 0; s >>= 1) acc[e] += __shfl_xor(acc[e], s);
    }
    if (l == 0) {
      float b1 = -1e30f, b2 = -1e30f;
      int i1 = 0, i2 = 0;
#pragma unroll
      for (int e = 0; e < NEXP; e++) {
        float v = acc[e];
        if (v > b1) { b2 = b1; i2 = i1; b1 = v; i1 = e; }
        else if (v > b2) { b2 = v; i2 = e; }
      }
      top_e[t * 2 + 0] = i1; top_e[t * 2 + 1] = i2;
      top_g[t * 2 + 0] = sigmoidf_(b1); top_g[t * 2 + 1] = sigmoidf_(b2);
    }
  }
}

// ---------------- scan: histogram of top_e -> counts/offs/cursor (1 block) ----------------
__global__ void k_scan(const int* __restrict__ top_e, int* __restrict__ counts,
                       int* __restrict__ offs, int* __restrict__ cursor) {
  __shared__ int hist[NEXP];
  int tid = threadIdx.x;
  if (tid < NEXP) hist[tid] = 0;
  __syncthreads();
  for (int i = tid; i < A_TOK * 2; i += 256) atomicAdd(&hist[top_e[i]], 1);
  __syncthreads();
  if (tid == 0) {
    int s = 0;
    for (int e = 0; e < NEXP; e++) { counts[e] = hist[e]; offs[e] = s; s += hist[e]; cursor[e] = 0; }
    counts[NEXP] = A_TOK;  // shared pseudo-expert
    offs[NEXP] = s;
  }
}

__global__ void k_dispatch(const float* __restrict__ x, const int* __restrict__ top_e,
                           const float* __restrict__ top_g, const int* __restrict__ offs,
                           int* __restrict__ cursor, int* __restrict__ slot_of,
                           __hip_bfloat16* __restrict__ y) {
  int t = blockIdx.x * 4 + (threadIdx.x >> 6);
  int l = threadIdx.x & 63;
  int e0 = top_e[t * 2 + 0], e1 = top_e[t * 2 + 1];
  float g0 = top_g[t * 2 + 0], g1 = top_g[t * 2 + 1];
  int s0 = 0, s1 = 0;
  if (l == 0) {
    s0 = offs[e0] + atomicAdd(&cursor[e0], 1);
    s1 = offs[e1] + atomicAdd(&cursor[e1], 1);
    slot_of[t * 2 + 0] = s0; slot_of[t * 2 + 1] = s1;
  }
  s0 = __shfl(s0, 0); s1 = __shfl(s1, 0);
  const float* xr = x + (size_t)t * DDIM;
#pragma unroll
  for (int i = 0; i < 16; i++) {
    int d = i * 64 + l;
    float v = xr[d];
    y[(size_t)s0 * DDIM + d] = __float2bfloat16(v * g0);
    y[(size_t)s1 * DDIM + d] = __float2bfloat16(v * g1);
  }
}

// ======== fused in+swiglu grouped GEMM (single interleaved B), 128x128, BK=32 ========
// R5's verified kernel, verbatim (3-D grid, no XCD swizzle).
__global__ __launch_bounds__(256, 3) void k_mlp1(
    const ushort* __restrict__ Abase, const ushort* __restrict__ Bbase,
    ushort* __restrict__ Obase, const int* __restrict__ d_cnt,
    const int* __restrict__ d_off) {
  constexpr int K = DDIM, NT = DDIM / 32;
  constexpr int BUF = 16384;
  __shared__ __align__(16) char smem[3 * BUF];
  int e = blockIdx.z;
  int cnt = d_cnt[e];
  int m0 = blockIdx.y * 128;
  if (m0 >= cnt) return;
  int roff = d_off[e];
  int n0 = blockIdx.x * 128;
  const ushort* B = Bbase + (size_t)e * NB1 * DDIM;
  int tid = threadIdx.x, w = tid >> 6, l = tid & 63;
  int wm = w >> 1, wn = w & 1, lr = l & 15, kg = l >> 4;
  size_t arow0 = (size_t)roff + m0;

  int srow = tid >> 2;
  int sgg = (tid & 3) ^ ((tid >> 3) & 3);
  const ushort* pA0 = Abase + (arow0 + srow) * (size_t)K + sgg * 8;
  const ushort* pA1 = pA0 + (size_t)64 * K;
  const ushort* pB0 = B + ((size_t)n0 + srow) * K + sgg * 8;
  const ushort* pB1 = pB0 + (size_t)64 * K;
  int tls = tid * 16;

  int xorg = (kg ^ ((lr >> 1) & 3)) << 4;
  int offA[4], offB[4];
#pragma unroll
  for (int i = 0; i < 4; i++) {
    offA[i] = (wm * 64 + i * 16 + lr) * 64 + xorg;
    offB[i] = 8192 + (wn * 64 + i * 16 + lr) * 64 + xorg;
  }

  f32x4 acc[4][4];
#pragma unroll
  for (int i = 0; i < 4; i++)
#pragma unroll
    for (int j = 0; j < 4; j++) acc[i][j] = {0.f, 0.f, 0.f, 0.f};

#pragma unroll
  for (int pt = 0; pt < 2; ++pt) {
    char* bb = smem + pt * BUF;
    lds16(pA0, bb + tls);         pA0 += 32;
    lds16(pA1, bb + 4096 + tls);  pA1 += 32;
    lds16(pB0, bb + 8192 + tls);  pB0 += 32;
    lds16(pB1, bb + 12288 + tls); pB1 += 32;
  }
  VMCNT(4);
  BARRIER();

  char* b0 = smem;
  char* b1 = smem + BUF;
  char* b2 = smem + 2 * BUF;
  for (int t = 0; t < NT; ++t) {
    bool st = (t + 2) < NT;
    short8v af[4], bf[4];
#pragma unroll
    for (int mf = 0; mf < 4; mf++) af[mf] = *(const short8v*)(b0 + offA[mf]);
#pragma unroll
    for (int nf = 0; nf < 2; nf++) bf[nf] = *(const short8v*)(b0 + offB[nf]);
    if (st) {
      lds16(pA0, b2 + tls);
      lds16(pA1, b2 + 4096 + tls);
    }
    pA0 += 32; pA1 += 32;
    BARRIER();
    __builtin_amdgcn_s_setprio(1);
#pragma unroll
    for (int nf = 0; nf < 2; nf++)
#pragma unroll
      for (int mf = 0; mf < 4; mf++)
        acc[mf][nf] = __builtin_amdgcn_mfma_f32_16x16x32_bf16(af[mf], bf[nf], acc[mf][nf], 0, 0, 0);
    __builtin_amdgcn_s_setprio(0);
    BARRIER();
#pragma unroll
    for (int nf = 2; nf < 4; nf++) bf[nf] = *(const short8v*)(b0 + offB[nf]);
    if (st) {
      lds16(pB0, b2 + 8192 + tls);
      lds16(pB1, b2 + 12288 + tls);
    }
    pB0 += 32; pB1 += 32;
    BARRIER();
    __builtin_amdgcn_s_setprio(1);
#pragma unroll
    for (int nf = 2; nf < 4; nf++)
#pragma unroll
      for (int mf = 0; mf < 4; mf++)
        acc[mf][nf] = __builtin_amdgcn_mfma_f32_16x16x32_bf16(af[mf], bf[nf], acc[mf][nf], 0, 0, 0);
    __builtin_amdgcn_s_setprio(0);
    if (t < NT - 1) {
      if (st) { VMCNT(4); } else { VMCNT(0); }
      BARRIER();
    }
    char* tmp = b0; b0 = b1; b1 = b2; b2 = tmp;
  }

  int j = (n0 >> 6) + wn;
#pragma unroll
  for (int mf = 0; mf < 4; mf++)
#pragma unroll
    for (int nf = 0; nf < 2; nf++)
#pragma unroll
      for (int r = 0; r < 4; r++) {
        int row = m0 + wm * 64 + mf * 16 + kg * 4 + r;
        if (row < cnt) {
          float mid = acc[mf][nf][r];
          float sw = acc[mf][nf + 2][r];
          float hv = mid * sigmoidf_(mid) * sw;
          int col = j * 32 + nf * 16 + lr;
          Obase[((size_t)roff + row) * FDIM + col] = f2bf(hv);
        }
      }
}

// ======== out-proj grouped GEMM, split-K=2, bf16 partials (R5 verbatim) ========
__global__ __launch_bounds__(256, 3) void k_mlp2(
    const ushort* __restrict__ Abase, const ushort* __restrict__ Bbase,
    ushort* __restrict__ part, const int* __restrict__ d_cnt,
    const int* __restrict__ d_off) {
  constexpr int K = FDIM, NT = 1024 / 32;
  constexpr int BUF = 16384;
  __shared__ __align__(16) char smem[3 * BUF];
  int e = blockIdx.z;
  int cnt = d_cnt[e];
  int mt = blockIdx.y >> 1, kz = blockIdx.y & 1;
  int m0 = mt * 128;
  if (m0 >= cnt) return;
  int roff = d_off[e];
  int n0 = blockIdx.x * 128;
  int kbeg = kz * 1024;
  const ushort* B = Bbase + (size_t)e * DDIM * FDIM;
  int tid = threadIdx.x, w = tid >> 6, l = tid & 63;
  int wm = w >> 1, wn = w & 1, lr = l & 15, kg = l >> 4;
  size_t arow0 = (size_t)roff + m0;

  int srow = tid >> 2;
  int sgg = (tid & 3) ^ ((tid >> 3) & 3);
  const ushort* pA0 = Abase + (arow0 + srow) * (size_t)K + kbeg + sgg * 8;
  const ushort* pA1 = pA0 + (size_t)64 * K;
  const ushort* pB0 = B + ((size_t)n0 + srow) * K + kbeg + sgg * 8;
  const ushort* pB1 = pB0 + (size_t)64 * K;
  int tls = tid * 16;

  int xorg = (kg ^ ((lr >> 1) & 3)) << 4;
  int offA[4], offB[4];
#pragma unroll
  for (int i = 0; i < 4; i++) {
    offA[i] = (wm * 64 + i * 16 + lr) * 64 + xorg;
    offB[i] = 8192 + (wn * 64 + i * 16 + lr) * 64 + xorg;
  }

  f32x4 acc[4][4];
#pragma unroll
  for (int i = 0; i < 4; i++)
#pragma unroll
    for (int j = 0; j < 4; j++) acc[i][j] = {0.f, 0.f, 0.f, 0.f};

#pragma unroll
  for (int pt = 0; pt < 2; ++pt) {
    char* bb = smem + pt * BUF;
    lds16(pA0, bb + tls);         pA0 += 32;
    lds16(pA1, bb + 4096 + tls);  pA1 += 32;
    lds16(pB0, bb + 8192 + tls);  pB0 += 32;
    lds16(pB1, bb + 12288 + tls); pB1 += 32;
  }
  VMCNT(4);
  BARRIER();

  char* b0 = smem;
  char* b1 = smem + BUF;
  char* b2 = smem + 2 * BUF;
  for (int t = 0; t < NT; ++t) {
    bool st = (t + 2) < NT;
    short8v af[4], bf[4];
#pragma unroll
    for (int mf = 0; mf < 4; mf++) af[mf] = *(const short8v*)(b0 + offA[mf]);
#pragma unroll
    for (int nf = 0; nf < 2; nf++) bf[nf] = *(const short8v*)(b0 + offB[nf]);
    if (st) {
      lds16(pA0, b2 + tls);
      lds16(pA1, b2 + 4096 + tls);
    }
    pA0 += 32; pA1 += 32;
    BARRIER();
    __builtin_amdgcn_s_setprio(1);
#pragma unroll
    for (int nf = 0; nf < 2; nf++)
#pragma unroll
      for (int mf = 0; mf < 4; mf++)
        acc[mf][nf] = __builtin_amdgcn_mfma_f32_16x16x32_bf16(af[mf], bf[nf], acc[mf][nf], 0, 0, 0);
    __builtin_amdgcn_s_setprio(0);
    BARRIER();
#pragma unroll
    for (int nf = 2; nf < 4; nf++) bf[nf] = *(const short8v*)(b0 + offB[nf]);
    if (st) {
      lds16(pB0, b2 + 8192 + tls);
      lds16(pB1, b2 + 12288 + tls);
    }
    pB0 += 32; pB1 += 32;
    BARRIER();
    __builtin_amdgcn_s_setprio(1);
#pragma unroll
    for (int nf = 2; nf < 4; nf++)
#pragma unroll
      for (int mf = 0; mf < 4; mf++)
        acc[mf][nf] = __builtin_amdgcn_mfma_f32_16x16x32_bf16(af[mf], bf[nf], acc[mf][nf], 0, 0, 0);
    __builtin_amdgcn_s_setprio(0);
    if (t < NT - 1) {
      if (st) { VMCNT(4); } else { VMCNT(0); }
      BARRIER();
    }
    char* tmp = b0; b0 = b1; b1 = b2; b2 = tmp;
  }

  ushort* outp = part + (size_t)kz * SLOTS_T * DDIM;
#pragma unroll
  for (int mf = 0; mf < 4; mf++)
#pragma unroll
    for (int nf = 0; nf < 4; nf++)
#pragma unroll
      for (int r = 0; r < 4; r++) {
        int row = m0 + wm * 64 + mf * 16 + kg * 4 + r;
        if (row < cnt) {
          int col = n0 + wn * 64 + nf * 16 + lr;
          outp[((size_t)roff + row) * DDIM + col] = f2bf(acc[mf][nf][r]);
        }
      }
}

// ------- combine: out[t][d] = sum over {2 kz} x {s0, s1, shared row} of bf16 partials ----
__global__ void k_combine(const ushort* __restrict__ part, const int* __restrict__ slot_of,
                          float* __restrict__ out) {
  int t = blockIdx.x, q = threadIdx.x;
  int rows[3];
  rows[0] = slot_of[t * 2 + 0];
  rows[1] = slot_of[t * 2 + 1];
  rows[2] = SLOTS_R + t;
  size_t P = (size_t)SLOTS_T * DDIM;
  float o[4] = {0.f, 0.f, 0.f, 0.f};
#pragma unroll
  for (int kz = 0; kz < 2; kz++)
#pragma unroll
    for (int i = 0; i < 3; i++) {
      ushort4v v = *(const ushort4v*)(part + kz * P + (size_t)rows[i] * DDIM + q * 4);
#pragma unroll
      for (int j = 0; j < 4; j++) o[j] += bf2f(v[j]);
    }
  float4 ov = {o[0], o[1], o[2], o[3]};
  ((float4*)out)[(size_t)t * (DDIM / 4) + q] = ov;
}

extern "C" void kernel_launch(void* const* d_in, const int* in_sizes, int n_in,
                              void* d_out, int out_size, void* d_ws, size_t ws_size,
                              hipStream_t stream) {
  (void)in_sizes; (void)n_in; (void)out_size; (void)ws_size;
  const float* x        = (const float*)d_in[0];
  const float* router   = (const float*)d_in[1];
  const float* w_in_sh  = (const float*)d_in[2];
  const float* w_out_sh = (const float*)d_in[3];
  const float* w_sw_sh  = (const float*)d_in[4];
  const float* w_in_e   = (const float*)d_in[5];
  const float* w_sw_e   = (const float*)d_in[6];
  const float* w_out_e  = (const float*)d_in[7];
  float* out = (float*)d_out;

  char* ws = (char*)d_ws;
  size_t off = 0;
  auto alloc = [&](size_t bytes) -> char* {
    char* p = ws + off;
    off += (bytes + 255) & ~(size_t)255;
    return p;
  };
  // Ordering: y_all ++ xbf ++ h contiguous (A overreads stay in-bounds; stores count-guarded).
  // part aliases wt12 (dead after k_mlp1; k_mlp2 reads wt_out_t + h only).
  ushort* wt12     = (ushort*)alloc((size_t)NE9 * NB1 * DDIM * 2);   // 75.5 MB
  ushort* wt_out_t = (ushort*)alloc((size_t)NE9 * DDIM * FDIM * 2);  // 37.7 MB
  __hip_bfloat16* y_all = (__hip_bfloat16*)alloc((size_t)SLOTS_R * DDIM * 2);
  __hip_bfloat16* xbf   = (__hip_bfloat16*)alloc((size_t)A_TOK * DDIM * 2);
  ushort* h        = (ushort*)alloc((size_t)SLOTS_T * FDIM * 2);     // 25.2 MB
  int*   counts  = (int*)alloc(64);
  int*   offs    = (int*)alloc(64);
  int*   cursor  = (int*)alloc(64);
  int*   top_e   = (int*)alloc((size_t)A_TOK * 2 * 4);
  float* top_g   = (float*)alloc((size_t)A_TOK * 2 * 4);
  int*   slot_of = (int*)alloc((size_t)A_TOK * 2 * 4);
  (void)alloc(1 << 20);  // guard for mlp2 A-tile overread
  ushort* part = wt12;   // [2][6144][1024] bf16 = 25.2 MB alias

  // 1) weight prep + router (one launch; router jobs are write-only)
  k_prep<<<dim3(PREP_NWG), 256, 0, stream>>>(
      w_in_e, w_sw_e, w_out_e, w_in_sh, w_sw_sh, w_out_sh,
      wt12, wt_out_t, x, router, xbf, top_e, top_g);

  // 2) scan: histogram top_e -> counts/offs/cursor (replaces memset+atomics+ticket)
  k_scan<<<dim3(1), 256, 0, stream>>>(top_e, counts, offs, cursor);

  // 3) dispatch
  k_dispatch<<<dim3(A_TOK / 4), 256, 0, stream>>>(x, top_e, top_g, offs, cursor, slot_of, y_all);

  // 4) fused in+swiglu (R5 grid)
  k_mlp1<<<dim3(NB1 / 128, A_TOK / 128, NE9), 256, 0, stream>>>(
      (const ushort*)y_all, wt12, h, counts, offs);

  // 5) out-proj, split-K=2 (R5 grid)
  k_mlp2<<<dim3(DDIM / 128, (A_TOK / 128) * 2, NE9), 256, 0, stream>>>(
      h, wt_out_t, part, counts, offs);

  // 6) combine (fully overwrites d_out -> poison-safe)
  k_combine<<<dim3(A_TOK), 256, 0, stream>>>(part, slot_of, out);
}

// Round 9
// 249.506 us; speedup vs baseline: 1.6372x; 1.0068x over previous
//
#include <hip/hip_runtime.h>
#include <hip/hip_bf16.h>

#define A_TOK 2048
#define DDIM 1024
#define FDIM 2048
#define NEXP 8
#define NE9 9                      // 8 routed + 1 shared pseudo-expert
#define SLOTS_R (2 * A_TOK)        // 4096 routed slots
#define SLOTS_T (SLOTS_R + A_TOK)  // 6144 incl. shared rows
#define NB1 (2 * FDIM)             // 4096: interleaved [w_in | w_swiglu] rows (32-col blocks)

// k_prep job ranges (flat 1-D grid); transpose jobs = 2 tiles (64x128) per block
#define PREP_TRA_END 4096                     // 16 z * 256 tile-pairs
#define PREP_TRB_END (PREP_TRA_END + 2048)    // 8 z * 256 tile-pairs
#define PREP_SH12_END (PREP_TRB_END + 1024)   // 4096 row-jobs / 4
#define PREP_SHOUT_END (PREP_SH12_END + 512)  // 1024 rows / 2
#define PREP_NWG (PREP_SHOUT_END + 512)       // + router jobs (2048 tokens / 4)

typedef __attribute__((ext_vector_type(8))) short short8v;   // 8 bf16
typedef __attribute__((ext_vector_type(4))) float f32x4;
typedef __attribute__((ext_vector_type(4))) ushort ushort4v;

#define BARRIER() asm volatile("s_barrier" ::: "memory")
#define VMCNT(n) asm volatile("s_waitcnt vmcnt(" #n ")" ::: "memory")

__device__ __forceinline__ void lds16(const void* g, void* l) {
  __builtin_amdgcn_global_load_lds((const __attribute__((address_space(1))) void*)g,
                                   (__attribute__((address_space(3))) void*)l, 16, 0, 0);
}

__device__ __forceinline__ float sigmoidf_(float x) { return 1.f / (1.f + __expf(-x)); }
__device__ __forceinline__ ushort f2bf(float x) {
  __hip_bfloat16 b = __float2bfloat16(x);
  ushort u; __builtin_memcpy(&u, &b, 2); return u;
}
__device__ __forceinline__ float bf2f(ushort u) {
  union { unsigned int i; float f; } x; x.i = (unsigned int)u << 16; return x.f;
}

// ============== consolidated prep: weight convert/transpose + router (one launch) ==============
// Transpose ranges: 2 tiles (64 rows x 128 cols) per block, register-staged loads (8 float4
// in flight before any LDS write) -> 2x in-flight bytes vs R8, half the blocks.
__global__ void k_prep(const float* __restrict__ w_in_e, const float* __restrict__ w_sw_e,
                       const float* __restrict__ w_out_e, const float* __restrict__ w_in_sh,
                       const float* __restrict__ w_sw_sh, const float* __restrict__ w_out_sh,
                       ushort* __restrict__ wt12, ushort* __restrict__ wt_out_t,
                       const float* __restrict__ x, const float* __restrict__ rw,
                       __hip_bfloat16* __restrict__ xbf, int* __restrict__ top_e,
                       float* __restrict__ top_g) {
  __shared__ ushort tile2[2][64][68];
  int b = blockIdx.x, tid = threadIdx.x;
  if (b < PREP_TRA_END) {
    // trA: w_in_e/w_sw_e [e][D][F] fp32 -> wt12[e][4096][1024] bf16 (interleaved remap)
    int z = b >> 8, p = b & 255;
    int e = z & 7, which = z >> 3;
    const float* in = (which ? w_sw_e : w_in_e) + (size_t)e * DDIM * FDIM;
    ushort* outb = wt12 + (size_t)e * NB1 * DDIM;
    int r0 = (p & 15) * 64, c0 = (p >> 4) * 128;   // r over D (16 tiles), c over F (16 pairs)
    int rr = tid >> 4, cq = tid & 15;
    float4 va[8];
#pragma unroll
    for (int u = 0; u < 2; u++)
#pragma unroll
      for (int i = 0; i < 4; i++) {
        int r = i * 16 + rr;
        va[u * 4 + i] = *(const float4*)(in + (size_t)(r0 + r) * FDIM + c0 + u * 64 + cq * 4);
      }
#pragma unroll
    for (int u = 0; u < 2; u++)
#pragma unroll
      for (int i = 0; i < 4; i++) {
        float4 v = va[u * 4 + i];
        ushort4v o = {f2bf(v.x), f2bf(v.y), f2bf(v.z), f2bf(v.w)};
        *(ushort4v*)&tile2[u][i * 16 + rr][cq * 4] = o;
      }
    __syncthreads();
    int cc = tid >> 4, rq = tid & 15;
#pragma unroll
    for (int u = 0; u < 2; u++)
#pragma unroll
      for (int i = 0; i < 4; i++) {
        int c = i * 16 + cc;
        int f = c0 + u * 64 + c;
        int rp = ((f >> 5) << 6) + (which << 5) + (f & 31);
        ushort4v o = {tile2[u][rq * 4 + 0][c], tile2[u][rq * 4 + 1][c],
                      tile2[u][rq * 4 + 2][c], tile2[u][rq * 4 + 3][c]};
        *(ushort4v*)(outb + (size_t)rp * DDIM + r0 + rq * 4) = o;
      }
  } else if (b < PREP_TRB_END) {
    // trB: w_out_e [e][F][D] fp32 -> wt_out_t [e][D][F] bf16 (plain transpose)
    int b2 = b - PREP_TRA_END;
    int z = b2 >> 8, p = b2 & 255;
    const float* in = w_out_e + (size_t)z * FDIM * DDIM;
    ushort* out = wt_out_t + (size_t)z * DDIM * FDIM;
    int r0 = (p >> 3) * 64, c0 = (p & 7) * 128;    // r over F (32 tiles), c over D (8 pairs)
    int rr = tid >> 4, cq = tid & 15;
    float4 va[8];
#pragma unroll
    for (int u = 0; u < 2; u++)
#pragma unroll
      for (int i = 0; i < 4; i++) {
        int r = i * 16 + rr;
        va[u * 4 + i] = *(const float4*)(in + (size_t)(r0 + r) * DDIM + c0 + u * 64 + cq * 4);
      }
#pragma unroll
    for (int u = 0; u < 2; u++)
#pragma unroll
      for (int i = 0; i < 4; i++) {
        float4 v = va[u * 4 + i];
        ushort4v o = {f2bf(v.x), f2bf(v.y), f2bf(v.z), f2bf(v.w)};
        *(ushort4v*)&tile2[u][i * 16 + rr][cq * 4] = o;
      }
    __syncthreads();
    int cc = tid >> 4, rq = tid & 15;
#pragma unroll
    for (int u = 0; u < 2; u++)
#pragma unroll
      for (int i = 0; i < 4; i++) {
        int c = i * 16 + cc;
        ushort4v o = {tile2[u][rq * 4 + 0][c], tile2[u][rq * 4 + 1][c],
                      tile2[u][rq * 4 + 2][c], tile2[u][rq * 4 + 3][c]};
        *(ushort4v*)(out + (size_t)(c0 + u * 64 + c) * FDIM + r0 + rq * 4) = o;
      }
  } else if (b < PREP_SH12_END) {
    // shared in/sw [F][D] -> wt12[8] rows (remap; already K-contiguous)
    int j = b - PREP_TRB_END;
    int rj = j * 4 + (tid >> 6);   // 0..4095
    int l = tid & 63;
    int which = rj & 1, f = rj >> 1;
    const float* src = (which ? w_sw_sh : w_in_sh) + (size_t)f * DDIM;
    int rp = ((f >> 5) << 6) + (which << 5) + (f & 31);
    ushort* dst = wt12 + (size_t)NEXP * NB1 * DDIM + (size_t)rp * DDIM;
#pragma unroll
    for (int i = 0; i < 4; i++) {
      int q = l + 64 * i;
      float4 v = ((const float4*)src)[q];
      ushort4v o = {f2bf(v.x), f2bf(v.y), f2bf(v.z), f2bf(v.w)};
      ((ushort4v*)dst)[q] = o;
    }
  } else if (b < PREP_SHOUT_END) {
    // shared out [D][F] -> wt_out_t[8] rows (plain convert)
    int j = b - PREP_SH12_END;
    int d = j * 2 + (tid >> 7);    // 0..1023
    int l = tid & 127;
    const float* src = w_out_sh + (size_t)d * FDIM;
    ushort* dst = wt_out_t + (size_t)NEXP * DDIM * FDIM + (size_t)d * FDIM;
#pragma unroll
    for (int i = 0; i < 4; i++) {
      int q = l + 128 * i;
      float4 v = ((const float4*)src)[q];
      ushort4v o = {f2bf(v.x), f2bf(v.y), f2bf(v.z), f2bf(v.w)};
      ((ushort4v*)dst)[q] = o;
    }
  } else {
    // router (write-only: no atomics, no pre-zeroed state)
    int j = b - PREP_SHOUT_END;
    int t = j * 4 + (tid >> 6);
    int l = tid & 63;
    const float* xr = x + (size_t)t * DDIM;
    float acc[NEXP];
#pragma unroll
    for (int e = 0; e < NEXP; e++) acc[e] = 0.f;
#pragma unroll
    for (int i = 0; i < 16; i++) {
      int d = i * 64 + l;
      float v = xr[d];
      xbf[(size_t)t * DDIM + d] = __float2bfloat16(v);
      const float* rr = rw + (size_t)d * NEXP;
#pragma unroll
      for (int e = 0; e < NEXP; e++) acc[e] += v * rr[e];
    }
#pragma unroll
    for (int e = 0; e < NEXP; e++) {
#pragma unroll
      for (int s = 32; s > 0; s >>= 1) acc[e] += __shfl_xor(acc[e], s);
    }
    if (l == 0) {
      float b1 = -1e30f, b2 = -1e30f;
      int i1 = 0, i2 = 0;
#pragma unroll
      for (int e = 0; e < NEXP; e++) {
        float v = acc[e];
        if (v > b1) { b2 = b1; i2 = i1; b1 = v; i1 = e; }
        else if (v > b2) { b2 = v; i2 = e; }
      }
      top_e[t * 2 + 0] = i1; top_e[t * 2 + 1] = i2;
      top_g[t * 2 + 0] = sigmoidf_(b1); top_g[t * 2 + 1] = sigmoidf_(b2);
    }
  }
}

// ---------------- scan: histogram of top_e -> counts/offs/cursor (1 block) ----------------
__global__ void k_scan(const int* __restrict__ top_e, int* __restrict__ counts,
                       int* __restrict__ offs, int* __restrict__ cursor) {
  __shared__ int hist[NEXP];
  int tid = threadIdx.x;
  if (tid < NEXP) hist[tid] = 0;
  __syncthreads();
  for (int i = tid; i < A_TOK * 2; i += 256) atomicAdd(&hist[top_e[i]], 1);
  __syncthreads();
  if (tid == 0) {
    int s = 0;
    for (int e = 0; e < NEXP; e++) { counts[e] = hist[e]; offs[e] = s; s += hist[e]; cursor[e] = 0; }
    counts[NEXP] = A_TOK;  // shared pseudo-expert
    offs[NEXP] = s;
  }
}

__global__ void k_dispatch(const float* __restrict__ x, const int* __restrict__ top_e,
                           const float* __restrict__ top_g, const int* __restrict__ offs,
                           int* __restrict__ cursor, int* __restrict__ slot_of,
                           __hip_bfloat16* __restrict__ y) {
  int t = blockIdx.x * 4 + (threadIdx.x >> 6);
  int l = threadIdx.x & 63;
  int e0 = top_e[t * 2 + 0], e1 = top_e[t * 2 + 1];
  float g0 = top_g[t * 2 + 0], g1 = top_g[t * 2 + 1];
  int s0 = 0, s1 = 0;
  if (l == 0) {
    s0 = offs[e0] + atomicAdd(&cursor[e0], 1);
    s1 = offs[e1] + atomicAdd(&cursor[e1], 1);
    slot_of[t * 2 + 0] = s0; slot_of[t * 2 + 1] = s1;
  }
  s0 = __shfl(s0, 0); s1 = __shfl(s1, 0);
  const float* xr = x + (size_t)t * DDIM;
#pragma unroll
  for (int i = 0; i < 16; i++) {
    int d = i * 64 + l;
    float v = xr[d];
    y[(size_t)s0 * DDIM + d] = __float2bfloat16(v * g0);
    y[(size_t)s1 * DDIM + d] = __float2bfloat16(v * g1);
  }
}

// ======== fused in+swiglu grouped GEMM (single interleaved B), 128x128, BK=32 ========
// R5's verified kernel, verbatim (3-D grid, no XCD swizzle).
__global__ __launch_bounds__(256, 3) void k_mlp1(
    const ushort* __restrict__ Abase, const ushort* __restrict__ Bbase,
    ushort* __restrict__ Obase, const int* __restrict__ d_cnt,
    const int* __restrict__ d_off) {
  constexpr int K = DDIM, NT = DDIM / 32;
  constexpr int BUF = 16384;
  __shared__ __align__(16) char smem[3 * BUF];
  int e = blockIdx.z;
  int cnt = d_cnt[e];
  int m0 = blockIdx.y * 128;
  if (m0 >= cnt) return;
  int roff = d_off[e];
  int n0 = blockIdx.x * 128;
  const ushort* B = Bbase + (size_t)e * NB1 * DDIM;
  int tid = threadIdx.x, w = tid >> 6, l = tid & 63;
  int wm = w >> 1, wn = w & 1, lr = l & 15, kg = l >> 4;
  size_t arow0 = (size_t)roff + m0;

  int srow = tid >> 2;
  int sgg = (tid & 3) ^ ((tid >> 3) & 3);
  const ushort* pA0 = Abase + (arow0 + srow) * (size_t)K + sgg * 8;
  const ushort* pA1 = pA0 + (size_t)64 * K;
  const ushort* pB0 = B + ((size_t)n0 + srow) * K + sgg * 8;
  const ushort* pB1 = pB0 + (size_t)64 * K;
  int tls = tid * 16;

  int xorg = (kg ^ ((lr >> 1) & 3)) << 4;
  int offA[4], offB[4];
#pragma unroll
  for (int i = 0; i < 4; i++) {
    offA[i] = (wm * 64 + i * 16 + lr) * 64 + xorg;
    offB[i] = 8192 + (wn * 64 + i * 16 + lr) * 64 + xorg;
  }

  f32x4 acc[4][4];
#pragma unroll
  for (int i = 0; i < 4; i++)
#pragma unroll
    for (int j = 0; j < 4; j++) acc[i][j] = {0.f, 0.f, 0.f, 0.f};

#pragma unroll
  for (int pt = 0; pt < 2; ++pt) {
    char* bb = smem + pt * BUF;
    lds16(pA0, bb + tls);         pA0 += 32;
    lds16(pA1, bb + 4096 + tls);  pA1 += 32;
    lds16(pB0, bb + 8192 + tls);  pB0 += 32;
    lds16(pB1, bb + 12288 + tls); pB1 += 32;
  }
  VMCNT(4);
  BARRIER();

  char* b0 = smem;
  char* b1 = smem + BUF;
  char* b2 = smem + 2 * BUF;
  for (int t = 0; t < NT; ++t) {
    bool st = (t + 2) < NT;
    short8v af[4], bf[4];
#pragma unroll
    for (int mf = 0; mf < 4; mf++) af[mf] = *(const short8v*)(b0 + offA[mf]);
#pragma unroll
    for (int nf = 0; nf < 2; nf++) bf[nf] = *(const short8v*)(b0 + offB[nf]);
    if (st) {
      lds16(pA0, b2 + tls);
      lds16(pA1, b2 + 4096 + tls);
    }
    pA0 += 32; pA1 += 32;
    BARRIER();
    __builtin_amdgcn_s_setprio(1);
#pragma unroll
    for (int nf = 0; nf < 2; nf++)
#pragma unroll
      for (int mf = 0; mf < 4; mf++)
        acc[mf][nf] = __builtin_amdgcn_mfma_f32_16x16x32_bf16(af[mf], bf[nf], acc[mf][nf], 0, 0, 0);
    __builtin_amdgcn_s_setprio(0);
    BARRIER();
#pragma unroll
    for (int nf = 2; nf < 4; nf++) bf[nf] = *(const short8v*)(b0 + offB[nf]);
    if (st) {
      lds16(pB0, b2 + 8192 + tls);
      lds16(pB1, b2 + 12288 + tls);
    }
    pB0 += 32; pB1 += 32;
    BARRIER();
    __builtin_amdgcn_s_setprio(1);
#pragma unroll
    for (int nf = 2; nf < 4; nf++)
#pragma unroll
      for (int mf = 0; mf < 4; mf++)
        acc[mf][nf] = __builtin_amdgcn_mfma_f32_16x16x32_bf16(af[mf], bf[nf], acc[mf][nf], 0, 0, 0);
    __builtin_amdgcn_s_setprio(0);
    if (t < NT - 1) {
      if (st) { VMCNT(4); } else { VMCNT(0); }
      BARRIER();
    }
    char* tmp = b0; b0 = b1; b1 = b2; b2 = tmp;
  }

  int j = (n0 >> 6) + wn;
#pragma unroll
  for (int mf = 0; mf < 4; mf++)
#pragma unroll
    for (int nf = 0; nf < 2; nf++)
#pragma unroll
      for (int r = 0; r < 4; r++) {
        int row = m0 + wm * 64 + mf * 16 + kg * 4 + r;
        if (row < cnt) {
          float mid = acc[mf][nf][r];
          float sw = acc[mf][nf + 2][r];
          float hv = mid * sigmoidf_(mid) * sw;
          int col = j * 32 + nf * 16 + lr;
          Obase[((size_t)roff + row) * FDIM + col] = f2bf(hv);
        }
      }
}

// ======== out-proj grouped GEMM, split-K=2, bf16 partials (R5 verbatim) ========
__global__ __launch_bounds__(256, 3) void k_mlp2(
    const ushort* __restrict__ Abase, const ushort* __restrict__ Bbase,
    ushort* __restrict__ part, const int* __restrict__ d_cnt,
    const int* __restrict__ d_off) {
  constexpr int K = FDIM, NT = 1024 / 32;
  constexpr int BUF = 16384;
  __shared__ __align__(16) char smem[3 * BUF];
  int e = blockIdx.z;
  int cnt = d_cnt[e];
  int mt = blockIdx.y >> 1, kz = blockIdx.y & 1;
  int m0 = mt * 128;
  if (m0 >= cnt) return;
  int roff = d_off[e];
  int n0 = blockIdx.x * 128;
  int kbeg = kz * 1024;
  const ushort* B = Bbase + (size_t)e * DDIM * FDIM;
  int tid = threadIdx.x, w = tid >> 6, l = tid & 63;
  int wm = w >> 1, wn = w & 1, lr = l & 15, kg = l >> 4;
  size_t arow0 = (size_t)roff + m0;

  int srow = tid >> 2;
  int sgg = (tid & 3) ^ ((tid >> 3) & 3);
  const ushort* pA0 = Abase + (arow0 + srow) * (size_t)K + kbeg + sgg * 8;
  const ushort* pA1 = pA0 + (size_t)64 * K;
  const ushort* pB0 = B + ((size_t)n0 + srow) * K + kbeg + sgg * 8;
  const ushort* pB1 = pB0 + (size_t)64 * K;
  int tls = tid * 16;

  int xorg = (kg ^ ((lr >> 1) & 3)) << 4;
  int offA[4], offB[4];
#pragma unroll
  for (int i = 0; i < 4; i++) {
    offA[i] = (wm * 64 + i * 16 + lr) * 64 + xorg;
    offB[i] = 8192 + (wn * 64 + i * 16 + lr) * 64 + xorg;
  }

  f32x4 acc[4][4];
#pragma unroll
  for (int i = 0; i < 4; i++)
#pragma unroll
    for (int j = 0; j < 4; j++) acc[i][j] = {0.f, 0.f, 0.f, 0.f};

#pragma unroll
  for (int pt = 0; pt < 2; ++pt) {
    char* bb = smem + pt * BUF;
    lds16(pA0, bb + tls);         pA0 += 32;
    lds16(pA1, bb + 4096 + tls);  pA1 += 32;
    lds16(pB0, bb + 8192 + tls);  pB0 += 32;
    lds16(pB1, bb + 12288 + tls); pB1 += 32;
  }
  VMCNT(4);
  BARRIER();

  char* b0 = smem;
  char* b1 = smem + BUF;
  char* b2 = smem + 2 * BUF;
  for (int t = 0; t < NT; ++t) {
    bool st = (t + 2) < NT;
    short8v af[4], bf[4];
#pragma unroll
    for (int mf = 0; mf < 4; mf++) af[mf] = *(const short8v*)(b0 + offA[mf]);
#pragma unroll
    for (int nf = 0; nf < 2; nf++) bf[nf] = *(const short8v*)(b0 + offB[nf]);
    if (st) {
      lds16(pA0, b2 + tls);
      lds16(pA1, b2 + 4096 + tls);
    }
    pA0 += 32; pA1 += 32;
    BARRIER();
    __builtin_amdgcn_s_setprio(1);
#pragma unroll
    for (int nf = 0; nf < 2; nf++)
#pragma unroll
      for (int mf = 0; mf < 4; mf++)
        acc[mf][nf] = __builtin_amdgcn_mfma_f32_16x16x32_bf16(af[mf], bf[nf], acc[mf][nf], 0, 0, 0);
    __builtin_amdgcn_s_setprio(0);
    BARRIER();
#pragma unroll
    for (int nf = 2; nf < 4; nf++) bf[nf] = *(const short8v*)(b0 + offB[nf]);
    if (st) {
      lds16(pB0, b2 + 8192 + tls);
      lds16(pB1, b2 + 12288 + tls);
    }
    pB0 += 32; pB1 += 32;
    BARRIER();
    __builtin_amdgcn_s_setprio(1);
#pragma unroll
    for (int nf = 2; nf < 4; nf++)
#pragma unroll
      for (int mf = 0; mf < 4; mf++)
        acc[mf][nf] = __builtin_amdgcn_mfma_f32_16x16x32_bf16(af[mf], bf[nf], acc[mf][nf], 0, 0, 0);
    __builtin_amdgcn_s_setprio(0);
    if (t < NT - 1) {
      if (st) { VMCNT(4); } else { VMCNT(0); }
      BARRIER();
    }
    char* tmp = b0; b0 = b1; b1 = b2; b2 = tmp;
  }

  ushort* outp = part + (size_t)kz * SLOTS_T * DDIM;
#pragma unroll
  for (int mf = 0; mf < 4; mf++)
#pragma unroll
    for (int nf = 0; nf < 4; nf++)
#pragma unroll
      for (int r = 0; r < 4; r++) {
        int row = m0 + wm * 64 + mf * 16 + kg * 4 + r;
        if (row < cnt) {
          int col = n0 + wn * 64 + nf * 16 + lr;
          outp[((size_t)roff + row) * DDIM + col] = f2bf(acc[mf][nf][r]);
        }
      }
}

// ------- combine: out[t][d] = sum over {2 kz} x {s0, s1, shared row} of bf16 partials ----
__global__ void k_combine(const ushort* __restrict__ part, const int* __restrict__ slot_of,
                          float* __restrict__ out) {
  int t = blockIdx.x, q = threadIdx.x;
  int rows[3];
  rows[0] = slot_of[t * 2 + 0];
  rows[1] = slot_of[t * 2 + 1];
  rows[2] = SLOTS_R + t;
  size_t P = (size_t)SLOTS_T * DDIM;
  float o[4] = {0.f, 0.f, 0.f, 0.f};
#pragma unroll
  for (int kz = 0; kz < 2; kz++)
#pragma unroll
    for (int i = 0; i < 3; i++) {
      ushort4v v = *(const ushort4v*)(part + kz * P + (size_t)rows[i] * DDIM + q * 4);
#pragma unroll
      for (int j = 0; j < 4; j++) o[j] += bf2f(v[j]);
    }
  float4 ov = {o[0], o[1], o[2], o[3]};
  ((float4*)out)[(size_t)t * (DDIM / 4) + q] = ov;
}

extern "C" void kernel_launch(void* const* d_in, const int* in_sizes, int n_in,
                              void* d_out, int out_size, void* d_ws, size_t ws_size,
                              hipStream_t stream) {
  (void)in_sizes; (void)n_in; (void)out_size; (void)ws_size;
  const float* x        = (const float*)d_in[0];
  const float* router   = (const float*)d_in[1];
  const float* w_in_sh  = (const float*)d_in[2];
  const float* w_out_sh = (const float*)d_in[3];
  const float* w_sw_sh  = (const float*)d_in[4];
  const float* w_in_e   = (const float*)d_in[5];
  const float* w_sw_e   = (const float*)d_in[6];
  const float* w_out_e  = (const float*)d_in[7];
  float* out = (float*)d_out;

  char* ws = (char*)d_ws;
  size_t off = 0;
  auto alloc = [&](size_t bytes) -> char* {
    char* p = ws + off;
    off += (bytes + 255) & ~(size_t)255;
    return p;
  };
  // Ordering: y_all ++ xbf ++ h contiguous (A overreads stay in-bounds; stores count-guarded).
  // part aliases wt12 (dead after k_mlp1; k_mlp2 reads wt_out_t + h only).
  ushort* wt12     = (ushort*)alloc((size_t)NE9 * NB1 * DDIM * 2);   // 75.5 MB
  ushort* wt_out_t = (ushort*)alloc((size_t)NE9 * DDIM * FDIM * 2);  // 37.7 MB
  __hip_bfloat16* y_all = (__hip_bfloat16*)alloc((size_t)SLOTS_R * DDIM * 2);
  __hip_bfloat16* xbf   = (__hip_bfloat16*)alloc((size_t)A_TOK * DDIM * 2);
  ushort* h        = (ushort*)alloc((size_t)SLOTS_T * FDIM * 2);     // 25.2 MB
  int*   counts  = (int*)alloc(64);
  int*   offs    = (int*)alloc(64);
  int*   cursor  = (int*)alloc(64);
  int*   top_e   = (int*)alloc((size_t)A_TOK * 2 * 4);
  float* top_g   = (float*)alloc((size_t)A_TOK * 2 * 4);
  int*   slot_of = (int*)alloc((size_t)A_TOK * 2 * 4);
  (void)alloc(1 << 20);  // guard for mlp2 A-tile overread
  ushort* part = wt12;   // [2][6144][1024] bf16 = 25.2 MB alias

  // 1) weight prep + router (one launch; router jobs are write-only)
  k_prep<<<dim3(PREP_NWG), 256, 0, stream>>>(
      w_in_e, w_sw_e, w_out_e, w_in_sh, w_sw_sh, w_out_sh,
      wt12, wt_out_t, x, router, xbf, top_e, top_g);

  // 2) scan: histogram top_e -> counts/offs/cursor
  k_scan<<<dim3(1), 256, 0, stream>>>(top_e, counts, offs, cursor);

  // 3) dispatch
  k_dispatch<<<dim3(A_TOK / 4), 256, 0, stream>>>(x, top_e, top_g, offs, cursor, slot_of, y_all);

  // 4) fused in+swiglu (R5 grid)
  k_mlp1<<<dim3(NB1 / 128, A_TOK / 128, NE9), 256, 0, stream>>>(
      (const ushort*)y_all, wt12, h, counts, offs);

  // 5) out-proj, split-K=2 (R5 grid)
  k_mlp2<<<dim3(DDIM / 128, (A_TOK / 128) * 2, NE9), 256, 0, stream>>>(
      h, wt_out_t, part, counts, offs);

  // 6) combine (fully overwrites d_out -> poison-safe)
  k_combine<<<dim3(A_TOK), 256, 0, stream>>>(part, slot_of, out);
}

// Round 10
// 249.167 us; speedup vs baseline: 1.6395x; 1.0014x over previous
//
#include <hip/hip_runtime.h>
#include <hip/hip_bf16.h>

#define A_TOK 2048
#define DDIM 1024
#define FDIM 2048
#define NEXP 8
#define NE9 9                      // 8 routed + 1 shared pseudo-expert
#define SLOTS_R (2 * A_TOK)        // 4096 routed slots
#define SLOTS_T (SLOTS_R + A_TOK)  // 6144 incl. shared rows
#define NB1 (2 * FDIM)             // 4096: interleaved [w_in | w_swiglu] rows (32-col blocks)

// k_prep job ranges: trA tiles now 128r x 64c (256B write segments); trB moved into k_mlp1
#define PREP_TRA_END 4096                     // 16 z * 256 tiles (8 r-tiles x 32 c-tiles)
#define PREP_SH12_END (PREP_TRA_END + 1024)   // 4096 row-jobs / 4
#define PREP_SHOUT_END (PREP_SH12_END + 512)  // 1024 rows / 2
#define PREP_NWG (PREP_SHOUT_END + 512)       // + router jobs (2048 tokens / 4)

typedef __attribute__((ext_vector_type(8))) short short8v;   // 8 bf16
typedef __attribute__((ext_vector_type(4))) float f32x4;
typedef __attribute__((ext_vector_type(4))) ushort ushort4v;

#define BARRIER() asm volatile("s_barrier" ::: "memory")
#define VMCNT(n) asm volatile("s_waitcnt vmcnt(" #n ")" ::: "memory")

__device__ __forceinline__ void lds16(const void* g, void* l) {
  __builtin_amdgcn_global_load_lds((const __attribute__((address_space(1))) void*)g,
                                   (__attribute__((address_space(3))) void*)l, 16, 0, 0);
}

__device__ __forceinline__ float sigmoidf_(float x) { return 1.f / (1.f + __expf(-x)); }
__device__ __forceinline__ ushort f2bf(float x) {
  __hip_bfloat16 b = __float2bfloat16(x);
  ushort u; __builtin_memcpy(&u, &b, 2); return u;
}
__device__ __forceinline__ float bf2f(ushort u) {
  union { unsigned int i; float f; } x; x.i = (unsigned int)u << 16; return x.f;
}

// ============== consolidated prep: trA + shared cvt + router (trB lives in k_mlp1) ==============
__global__ void k_prep(const float* __restrict__ w_in_e, const float* __restrict__ w_sw_e,
                       const float* __restrict__ w_in_sh, const float* __restrict__ w_sw_sh,
                       const float* __restrict__ w_out_sh,
                       ushort* __restrict__ wt12, ushort* __restrict__ wt_out_t,
                       const float* __restrict__ x, const float* __restrict__ rw,
                       __hip_bfloat16* __restrict__ xbf, int* __restrict__ top_e,
                       float* __restrict__ top_g) {
  __shared__ ushort tile[128][68];   // 17408 B; row stride 136B (8B-aligned for b64 ops)
  int b = blockIdx.x, tid = threadIdx.x;
  if (b < PREP_TRA_END) {
    // trA: w_in_e/w_sw_e [e][D][F] fp32 -> wt12[e][4096][1024] bf16 (interleaved remap)
    // tile = 128 r (over D) x 64 c (over F): each output rp-row gets 128 elems = 256B.
    int z = b >> 8, p = b & 255;
    int e = z & 7, which = z >> 3;
    const float* in = (which ? w_sw_e : w_in_e) + (size_t)e * DDIM * FDIM;
    ushort* outb = wt12 + (size_t)e * NB1 * DDIM;
    int r0 = (p & 7) * 128, c0 = (p >> 3) * 64;   // r over D (8 tiles), c over F (32 tiles)
    int rr = tid >> 4, cq = tid & 15;
    float4 va[8];
#pragma unroll
    for (int i = 0; i < 8; i++)
      va[i] = *(const float4*)(in + (size_t)(r0 + i * 16 + rr) * FDIM + c0 + cq * 4);
#pragma unroll
    for (int i = 0; i < 8; i++) {
      float4 v = va[i];
      ushort4v o = {f2bf(v.x), f2bf(v.y), f2bf(v.z), f2bf(v.w)};
      *(ushort4v*)&tile[i * 16 + rr][cq * 4] = o;
    }
    __syncthreads();
    int cc = tid >> 5, rq = tid & 31;
#pragma unroll
    for (int i = 0; i < 8; i++) {
      int c = i * 8 + cc;
      int f = c0 + c;
      int rp = ((f >> 5) << 6) + (which << 5) + (f & 31);
      ushort4v o = {tile[rq * 4 + 0][c], tile[rq * 4 + 1][c],
                    tile[rq * 4 + 2][c], tile[rq * 4 + 3][c]};
      *(ushort4v*)(outb + (size_t)rp * DDIM + r0 + rq * 4) = o;
    }
  } else if (b < PREP_SH12_END) {
    // shared in/sw [F][D] -> wt12[8] rows (remap; already K-contiguous)
    int j = b - PREP_TRA_END;
    int rj = j * 4 + (tid >> 6);   // 0..4095
    int l = tid & 63;
    int which = rj & 1, f = rj >> 1;
    const float* src = (which ? w_sw_sh : w_in_sh) + (size_t)f * DDIM;
    int rp = ((f >> 5) << 6) + (which << 5) + (f & 31);
    ushort* dst = wt12 + (size_t)NEXP * NB1 * DDIM + (size_t)rp * DDIM;
#pragma unroll
    for (int i = 0; i < 4; i++) {
      int q = l + 64 * i;
      float4 v = ((const float4*)src)[q];
      ushort4v o = {f2bf(v.x), f2bf(v.y), f2bf(v.z), f2bf(v.w)};
      ((ushort4v*)dst)[q] = o;
    }
  } else if (b < PREP_SHOUT_END) {
    // shared out [D][F] -> wt_out_t[8] rows (plain convert)
    int j = b - PREP_SH12_END;
    int d = j * 2 + (tid >> 7);    // 0..1023
    int l = tid & 127;
    const float* src = w_out_sh + (size_t)d * FDIM;
    ushort* dst = wt_out_t + (size_t)NEXP * DDIM * FDIM + (size_t)d * FDIM;
#pragma unroll
    for (int i = 0; i < 4; i++) {
      int q = l + 128 * i;
      float4 v = ((const float4*)src)[q];
      ushort4v o = {f2bf(v.x), f2bf(v.y), f2bf(v.z), f2bf(v.w)};
      ((ushort4v*)dst)[q] = o;
    }
  } else {
    // router (write-only: no atomics, no pre-zeroed state)
    int j = b - PREP_SHOUT_END;
    int t = j * 4 + (tid >> 6);
    int l = tid & 63;
    const float* xr = x + (size_t)t * DDIM;
    float acc[NEXP];
#pragma unroll
    for (int e = 0; e < NEXP; e++) acc[e] = 0.f;
#pragma unroll
    for (int i = 0; i < 16; i++) {
      int d = i * 64 + l;
      float v = xr[d];
      xbf[(size_t)t * DDIM + d] = __float2bfloat16(v);
      const float* rr = rw + (size_t)d * NEXP;
#pragma unroll
      for (int e = 0; e < NEXP; e++) acc[e] += v * rr[e];
    }
#pragma unroll
    for (int e = 0; e < NEXP; e++) {
#pragma unroll
      for (int s = 32; s > 0; s >>= 1) acc[e] += __shfl_xor(acc[e], s);
    }
    if (l == 0) {
      float b1 = -1e30f, b2 = -1e30f;
      int i1 = 0, i2 = 0;
#pragma unroll
      for (int e = 0; e < NEXP; e++) {
        float v = acc[e];
        if (v > b1) { b2 = b1; i2 = i1; b1 = v; i1 = e; }
        else if (v > b2) { b2 = v; i2 = e; }
      }
      top_e[t * 2 + 0] = i1; top_e[t * 2 + 1] = i2;
      top_g[t * 2 + 0] = sigmoidf_(b1); top_g[t * 2 + 1] = sigmoidf_(b2);
    }
  }
}

// ---------------- scan: histogram of top_e -> counts/offs/cursor (1 block) ----------------
__global__ void k_scan(const int* __restrict__ top_e, int* __restrict__ counts,
                       int* __restrict__ offs, int* __restrict__ cursor) {
  __shared__ int hist[NEXP];
  int tid = threadIdx.x;
  if (tid < NEXP) hist[tid] = 0;
  __syncthreads();
  for (int i = tid; i < A_TOK * 2; i += 256) atomicAdd(&hist[top_e[i]], 1);
  __syncthreads();
  if (tid == 0) {
    int s = 0;
    for (int e = 0; e < NEXP; e++) { counts[e] = hist[e]; offs[e] = s; s += hist[e]; cursor[e] = 0; }
    counts[NEXP] = A_TOK;  // shared pseudo-expert
    offs[NEXP] = s;
  }
}

__global__ void k_dispatch(const float* __restrict__ x, const int* __restrict__ top_e,
                           const float* __restrict__ top_g, const int* __restrict__ offs,
                           int* __restrict__ cursor, int* __restrict__ slot_of,
                           __hip_bfloat16* __restrict__ y) {
  int t = blockIdx.x * 4 + (threadIdx.x >> 6);
  int l = threadIdx.x & 63;
  int e0 = top_e[t * 2 + 0], e1 = top_e[t * 2 + 1];
  float g0 = top_g[t * 2 + 0], g1 = top_g[t * 2 + 1];
  int s0 = 0, s1 = 0;
  if (l == 0) {
    s0 = offs[e0] + atomicAdd(&cursor[e0], 1);
    s1 = offs[e1] + atomicAdd(&cursor[e1], 1);
    slot_of[t * 2 + 0] = s0; slot_of[t * 2 + 1] = s1;
  }
  s0 = __shfl(s0, 0); s1 = __shfl(s1, 0);
  const float* xr = x + (size_t)t * DDIM;
#pragma unroll
  for (int i = 0; i < 16; i++) {
    int d = i * 64 + l;
    float v = xr[d];
    y[(size_t)s0 * DDIM + d] = __float2bfloat16(v * g0);
    y[(size_t)s1 * DDIM + d] = __float2bfloat16(v * g1);
  }
}

// ======== k_mlp1: z<4 = trB transpose jobs (overlap with GEMM); z>=4 = grouped GEMM ========
// GEMM part is R5's verified kernel verbatim (e = z - 4).
__global__ __launch_bounds__(256, 3) void k_mlp1(
    const ushort* __restrict__ Abase, const ushort* __restrict__ Bbase,
    ushort* __restrict__ Obase, const int* __restrict__ d_cnt,
    const int* __restrict__ d_off, const float* __restrict__ w_out_e,
    ushort* __restrict__ wt_out_t) {
  constexpr int K = DDIM, NT = DDIM / 32;
  constexpr int BUF = 16384;
  __shared__ __align__(16) char smem[3 * BUF];
  int z = blockIdx.z;
  int tid = threadIdx.x;
  if (z < 4) {
    // trB: w_out_e [e][F][D] fp32 -> wt_out_t [e][D][F] bf16; 128r(F) x 64c(D) tiles
    ushort (*tile)[68] = (ushort(*)[68])smem;
    int jj = (z * 16 + blockIdx.y) * 32 + blockIdx.x;  // 0..2047
    int ex = jj >> 8, p = jj & 255;                    // 256 tiles/expert
    const float* in = w_out_e + (size_t)ex * FDIM * DDIM;
    ushort* outp = wt_out_t + (size_t)ex * DDIM * FDIM;
    int r0 = (p >> 4) * 128, c0 = (p & 15) * 64;       // r over F (16), c over D (16)
    int rr = tid >> 4, cq = tid & 15;
    float4 va[8];
#pragma unroll
    for (int i = 0; i < 8; i++)
      va[i] = *(const float4*)(in + (size_t)(r0 + i * 16 + rr) * DDIM + c0 + cq * 4);
#pragma unroll
    for (int i = 0; i < 8; i++) {
      float4 v = va[i];
      ushort4v o = {f2bf(v.x), f2bf(v.y), f2bf(v.z), f2bf(v.w)};
      *(ushort4v*)&tile[i * 16 + rr][cq * 4] = o;
    }
    __syncthreads();
    int cc = tid >> 5, rq = tid & 31;
#pragma unroll
    for (int i = 0; i < 8; i++) {
      int c = i * 8 + cc;
      ushort4v o = {tile[rq * 4 + 0][c], tile[rq * 4 + 1][c],
                    tile[rq * 4 + 2][c], tile[rq * 4 + 3][c]};
      *(ushort4v*)(outp + (size_t)(c0 + c) * FDIM + r0 + rq * 4) = o;
    }
    return;
  }
  int e = z - 4;
  int cnt = d_cnt[e];
  int m0 = blockIdx.y * 128;
  if (m0 >= cnt) return;
  int roff = d_off[e];
  int n0 = blockIdx.x * 128;
  const ushort* B = Bbase + (size_t)e * NB1 * DDIM;
  int w = tid >> 6, l = tid & 63;
  int wm = w >> 1, wn = w & 1, lr = l & 15, kg = l >> 4;
  size_t arow0 = (size_t)roff + m0;

  int srow = tid >> 2;
  int sgg = (tid & 3) ^ ((tid >> 3) & 3);
  const ushort* pA0 = Abase + (arow0 + srow) * (size_t)K + sgg * 8;
  const ushort* pA1 = pA0 + (size_t)64 * K;
  const ushort* pB0 = B + ((size_t)n0 + srow) * K + sgg * 8;
  const ushort* pB1 = pB0 + (size_t)64 * K;
  int tls = tid * 16;

  int xorg = (kg ^ ((lr >> 1) & 3)) << 4;
  int offA[4], offB[4];
#pragma unroll
  for (int i = 0; i < 4; i++) {
    offA[i] = (wm * 64 + i * 16 + lr) * 64 + xorg;
    offB[i] = 8192 + (wn * 64 + i * 16 + lr) * 64 + xorg;
  }

  f32x4 acc[4][4];
#pragma unroll
  for (int i = 0; i < 4; i++)
#pragma unroll
    for (int j = 0; j < 4; j++) acc[i][j] = {0.f, 0.f, 0.f, 0.f};

#pragma unroll
  for (int pt = 0; pt < 2; ++pt) {
    char* bb = smem + pt * BUF;
    lds16(pA0, bb + tls);         pA0 += 32;
    lds16(pA1, bb + 4096 + tls);  pA1 += 32;
    lds16(pB0, bb + 8192 + tls);  pB0 += 32;
    lds16(pB1, bb + 12288 + tls); pB1 += 32;
  }
  VMCNT(4);
  BARRIER();

  char* b0 = smem;
  char* b1 = smem + BUF;
  char* b2 = smem + 2 * BUF;
  for (int t = 0; t < NT; ++t) {
    bool st = (t + 2) < NT;
    short8v af[4], bf[4];
#pragma unroll
    for (int mf = 0; mf < 4; mf++) af[mf] = *(const short8v*)(b0 + offA[mf]);
#pragma unroll
    for (int nf = 0; nf < 2; nf++) bf[nf] = *(const short8v*)(b0 + offB[nf]);
    if (st) {
      lds16(pA0, b2 + tls);
      lds16(pA1, b2 + 4096 + tls);
    }
    pA0 += 32; pA1 += 32;
    BARRIER();
    __builtin_amdgcn_s_setprio(1);
#pragma unroll
    for (int nf = 0; nf < 2; nf++)
#pragma unroll
      for (int mf = 0; mf < 4; mf++)
        acc[mf][nf] = __builtin_amdgcn_mfma_f32_16x16x32_bf16(af[mf], bf[nf], acc[mf][nf], 0, 0, 0);
    __builtin_amdgcn_s_setprio(0);
    BARRIER();
#pragma unroll
    for (int nf = 2; nf < 4; nf++) bf[nf] = *(const short8v*)(b0 + offB[nf]);
    if (st) {
      lds16(pB0, b2 + 8192 + tls);
      lds16(pB1, b2 + 12288 + tls);
    }
    pB0 += 32; pB1 += 32;
    BARRIER();
    __builtin_amdgcn_s_setprio(1);
#pragma unroll
    for (int nf = 2; nf < 4; nf++)
#pragma unroll
      for (int mf = 0; mf < 4; mf++)
        acc[mf][nf] = __builtin_amdgcn_mfma_f32_16x16x32_bf16(af[mf], bf[nf], acc[mf][nf], 0, 0, 0);
    __builtin_amdgcn_s_setprio(0);
    if (t < NT - 1) {
      if (st) { VMCNT(4); } else { VMCNT(0); }
      BARRIER();
    }
    char* tmp = b0; b0 = b1; b1 = b2; b2 = tmp;
  }

  int j = (n0 >> 6) + wn;
#pragma unroll
  for (int mf = 0; mf < 4; mf++)
#pragma unroll
    for (int nf = 0; nf < 2; nf++)
#pragma unroll
      for (int r = 0; r < 4; r++) {
        int row = m0 + wm * 64 + mf * 16 + kg * 4 + r;
        if (row < cnt) {
          float mid = acc[mf][nf][r];
          float sw = acc[mf][nf + 2][r];
          float hv = mid * sigmoidf_(mid) * sw;
          int col = j * 32 + nf * 16 + lr;
          Obase[((size_t)roff + row) * FDIM + col] = f2bf(hv);
        }
      }
}

// ======== out-proj grouped GEMM, split-K=2, bf16 partials (R5 verbatim) ========
__global__ __launch_bounds__(256, 3) void k_mlp2(
    const ushort* __restrict__ Abase, const ushort* __restrict__ Bbase,
    ushort* __restrict__ part, const int* __restrict__ d_cnt,
    const int* __restrict__ d_off) {
  constexpr int K = FDIM, NT = 1024 / 32;
  constexpr int BUF = 16384;
  __shared__ __align__(16) char smem[3 * BUF];
  int e = blockIdx.z;
  int cnt = d_cnt[e];
  int mt = blockIdx.y >> 1, kz = blockIdx.y & 1;
  int m0 = mt * 128;
  if (m0 >= cnt) return;
  int roff = d_off[e];
  int n0 = blockIdx.x * 128;
  int kbeg = kz * 1024;
  const ushort* B = Bbase + (size_t)e * DDIM * FDIM;
  int tid = threadIdx.x, w = tid >> 6, l = tid & 63;
  int wm = w >> 1, wn = w & 1, lr = l & 15, kg = l >> 4;
  size_t arow0 = (size_t)roff + m0;

  int srow = tid >> 2;
  int sgg = (tid & 3) ^ ((tid >> 3) & 3);
  const ushort* pA0 = Abase + (arow0 + srow) * (size_t)K + kbeg + sgg * 8;
  const ushort* pA1 = pA0 + (size_t)64 * K;
  const ushort* pB0 = B + ((size_t)n0 + srow) * K + kbeg + sgg * 8;
  const ushort* pB1 = pB0 + (size_t)64 * K;
  int tls = tid * 16;

  int xorg = (kg ^ ((lr >> 1) & 3)) << 4;
  int offA[4], offB[4];
#pragma unroll
  for (int i = 0; i < 4; i++) {
    offA[i] = (wm * 64 + i * 16 + lr) * 64 + xorg;
    offB[i] = 8192 + (wn * 64 + i * 16 + lr) * 64 + xorg;
  }

  f32x4 acc[4][4];
#pragma unroll
  for (int i = 0; i < 4; i++)
#pragma unroll
    for (int j = 0; j < 4; j++) acc[i][j] = {0.f, 0.f, 0.f, 0.f};

#pragma unroll
  for (int pt = 0; pt < 2; ++pt) {
    char* bb = smem + pt * BUF;
    lds16(pA0, bb + tls);         pA0 += 32;
    lds16(pA1, bb + 4096 + tls);  pA1 += 32;
    lds16(pB0, bb + 8192 + tls);  pB0 += 32;
    lds16(pB1, bb + 12288 + tls); pB1 += 32;
  }
  VMCNT(4);
  BARRIER();

  char* b0 = smem;
  char* b1 = smem + BUF;
  char* b2 = smem + 2 * BUF;
  for (int t = 0; t < NT; ++t) {
    bool st = (t + 2) < NT;
    short8v af[4], bf[4];
#pragma unroll
    for (int mf = 0; mf < 4; mf++) af[mf] = *(const short8v*)(b0 + offA[mf]);
#pragma unroll
    for (int nf = 0; nf < 2; nf++) bf[nf] = *(const short8v*)(b0 + offB[nf]);
    if (st) {
      lds16(pA0, b2 + tls);
      lds16(pA1, b2 + 4096 + tls);
    }
    pA0 += 32; pA1 += 32;
    BARRIER();
    __builtin_amdgcn_s_setprio(1);
#pragma unroll
    for (int nf = 0; nf < 2; nf++)
#pragma unroll
      for (int mf = 0; mf < 4; mf++)
        acc[mf][nf] = __builtin_amdgcn_mfma_f32_16x16x32_bf16(af[mf], bf[nf], acc[mf][nf], 0, 0, 0);
    __builtin_amdgcn_s_setprio(0);
    BARRIER();
#pragma unroll
    for (int nf = 2; nf < 4; nf++) bf[nf] = *(const short8v*)(b0 + offB[nf]);
    if (st) {
      lds16(pB0, b2 + 8192 + tls);
      lds16(pB1, b2 + 12288 + tls);
    }
    pB0 += 32; pB1 += 32;
    BARRIER();
    __builtin_amdgcn_s_setprio(1);
#pragma unroll
    for (int nf = 2; nf < 4; nf++)
#pragma unroll
      for (int mf = 0; mf < 4; mf++)
        acc[mf][nf] = __builtin_amdgcn_mfma_f32_16x16x32_bf16(af[mf], bf[nf], acc[mf][nf], 0, 0, 0);
    __builtin_amdgcn_s_setprio(0);
    if (t < NT - 1) {
      if (st) { VMCNT(4); } else { VMCNT(0); }
      BARRIER();
    }
    char* tmp = b0; b0 = b1; b1 = b2; b2 = tmp;
  }

  ushort* outp = part + (size_t)kz * SLOTS_T * DDIM;
#pragma unroll
  for (int mf = 0; mf < 4; mf++)
#pragma unroll
    for (int nf = 0; nf < 4; nf++)
#pragma unroll
      for (int r = 0; r < 4; r++) {
        int row = m0 + wm * 64 + mf * 16 + kg * 4 + r;
        if (row < cnt) {
          int col = n0 + wn * 64 + nf * 16 + lr;
          outp[((size_t)roff + row) * DDIM + col] = f2bf(acc[mf][nf][r]);
        }
      }
}

// ------- combine: out[t][d] = sum over {2 kz} x {s0, s1, shared row} of bf16 partials ----
__global__ void k_combine(const ushort* __restrict__ part, const int* __restrict__ slot_of,
                          float* __restrict__ out) {
  int t = blockIdx.x, q = threadIdx.x;
  int rows[3];
  rows[0] = slot_of[t * 2 + 0];
  rows[1] = slot_of[t * 2 + 1];
  rows[2] = SLOTS_R + t;
  size_t P = (size_t)SLOTS_T * DDIM;
  float o[4] = {0.f, 0.f, 0.f, 0.f};
#pragma unroll
  for (int kz = 0; kz < 2; kz++)
#pragma unroll
    for (int i = 0; i < 3; i++) {
      ushort4v v = *(const ushort4v*)(part + kz * P + (size_t)rows[i] * DDIM + q * 4);
#pragma unroll
      for (int j = 0; j < 4; j++) o[j] += bf2f(v[j]);
    }
  float4 ov = {o[0], o[1], o[2], o[3]};
  ((float4*)out)[(size_t)t * (DDIM / 4) + q] = ov;
}

extern "C" void kernel_launch(void* const* d_in, const int* in_sizes, int n_in,
                              void* d_out, int out_size, void* d_ws, size_t ws_size,
                              hipStream_t stream) {
  (void)in_sizes; (void)n_in; (void)out_size; (void)ws_size;
  const float* x        = (const float*)d_in[0];
  const float* router   = (const float*)d_in[1];
  const float* w_in_sh  = (const float*)d_in[2];
  const float* w_out_sh = (const float*)d_in[3];
  const float* w_sw_sh  = (const float*)d_in[4];
  const float* w_in_e   = (const float*)d_in[5];
  const float* w_sw_e   = (const float*)d_in[6];
  const float* w_out_e  = (const float*)d_in[7];
  float* out = (float*)d_out;

  char* ws = (char*)d_ws;
  size_t off = 0;
  auto alloc = [&](size_t bytes) -> char* {
    char* p = ws + off;
    off += (bytes + 255) & ~(size_t)255;
    return p;
  };
  // Ordering: y_all ++ xbf ++ h contiguous (A overreads stay in-bounds; stores count-guarded).
  // part aliases wt12 (dead after k_mlp1; k_mlp2 reads wt_out_t + h only).
  ushort* wt12     = (ushort*)alloc((size_t)NE9 * NB1 * DDIM * 2);   // 75.5 MB
  ushort* wt_out_t = (ushort*)alloc((size_t)NE9 * DDIM * FDIM * 2);  // 37.7 MB
  __hip_bfloat16* y_all = (__hip_bfloat16*)alloc((size_t)SLOTS_R * DDIM * 2);
  __hip_bfloat16* xbf   = (__hip_bfloat16*)alloc((size_t)A_TOK * DDIM * 2);
  ushort* h        = (ushort*)alloc((size_t)SLOTS_T * FDIM * 2);     // 25.2 MB
  int*   counts  = (int*)alloc(64);
  int*   offs    = (int*)alloc(64);
  int*   cursor  = (int*)alloc(64);
  int*   top_e   = (int*)alloc((size_t)A_TOK * 2 * 4);
  float* top_g   = (float*)alloc((size_t)A_TOK * 2 * 4);
  int*   slot_of = (int*)alloc((size_t)A_TOK * 2 * 4);
  (void)alloc(1 << 20);  // guard for mlp2 A-tile overread
  ushort* part = wt12;   // [2][6144][1024] bf16 = 25.2 MB alias

  // 1) prep: trA + shared converts + router (trB moved into k_mlp1)
  k_prep<<<dim3(PREP_NWG), 256, 0, stream>>>(
      w_in_e, w_sw_e, w_in_sh, w_sw_sh, w_out_sh,
      wt12, wt_out_t, x, router, xbf, top_e, top_g);

  // 2) scan: histogram top_e -> counts/offs/cursor
  k_scan<<<dim3(1), 256, 0, stream>>>(top_e, counts, offs, cursor);

  // 3) dispatch
  k_dispatch<<<dim3(A_TOK / 4), 256, 0, stream>>>(x, top_e, top_g, offs, cursor, slot_of, y_all);

  // 4) fused in+swiglu GEMM (z>=4) + trB transpose jobs (z<4, overlap)
  k_mlp1<<<dim3(NB1 / 128, A_TOK / 128, 4 + NE9), 256, 0, stream>>>(
      (const ushort*)y_all, wt12, h, counts, offs, w_out_e, wt_out_t);

  // 5) out-proj, split-K=2 (reads wt_out_t written in step 4 — stream-ordered)
  k_mlp2<<<dim3(DDIM / 128, (A_TOK / 128) * 2, NE9), 256, 0, stream>>>(
      h, wt_out_t, part, counts, offs);

  // 6) combine (fully overwrites d_out -> poison-safe)
  k_combine<<<dim3(A_TOK), 256, 0, stream>>>(part, slot_of, out);
}